// Round 1
// baseline (674.388 us; speedup 1.0000x reference)
//
#include <hip/hip_runtime.h>

// ---------------------------------------------------------------------------
// TransformerBlock: B=8, T=1024, E=1024, H=16, HS=64, FF=4096
// Strategy: bf16 MFMA (16x16x32) for all GEMMs; bf16x3 split (hi/lo) on the
// numerically-sensitive path (LN1out -> Q,K proj, and QK^T) because the
// reference multiplies scores by sqrt(T)=32 (std ~256 -> near-one-hot softmax).
// ---------------------------------------------------------------------------

typedef unsigned short u16;
typedef __attribute__((ext_vector_type(8))) short  bfx8;
typedef __attribute__((ext_vector_type(4))) float  f32x4;
typedef __attribute__((ext_vector_type(4))) unsigned short u16v4;

#define MFMA16 __builtin_amdgcn_mfma_f32_16x16x32_bf16

__device__ __forceinline__ u16 f2bf(float f) {
    union { float f; unsigned u; } c; c.f = f;
    unsigned r = c.u + 0x7fffu + ((c.u >> 16) & 1u);
    return (u16)(r >> 16);
}
__device__ __forceinline__ float bf2f(u16 b) {
    union { unsigned u; float f; } c; c.u = ((unsigned)b) << 16; return c.f;
}

__device__ __forceinline__ void gl_lds16(const void* g, void* l) {
    void* gg = (void*)g;
    __builtin_amdgcn_global_load_lds(
        (__attribute__((address_space(1))) void*)gg,
        (__attribute__((address_space(3))) void*)l,
        16, 0, 0);
}

// ---------------------------------------------------------------------------
// Generic 64x64-tiled transpose: src f32 [R][C] (row-major) -> dst bf16 [C][R]
// (dst row stride OS). Optional hi/lo split. Batched via blockIdx.z.
// ---------------------------------------------------------------------------
__global__ __launch_bounds__(256)
void transpose_split(const float* __restrict__ src, u16* __restrict__ dhi,
                     u16* __restrict__ dlo, int C, int OS,
                     size_t inBS, size_t outBS)
{
    __shared__ float t[64][65];
    const int tid = threadIdx.x;
    const float* s = src + (size_t)blockIdx.z * inBS
                   + ((size_t)blockIdx.y * 64) * C + (size_t)blockIdx.x * 64;
    const size_t obase = (size_t)blockIdx.z * outBS
                       + ((size_t)blockIdx.x * 64) * OS + (size_t)blockIdx.y * 64;
    {
        const int r = tid >> 2, c4 = (tid & 3) * 16;
#pragma unroll
        for (int k = 0; k < 4; ++k) {
            float4 f = *(const float4*)(s + (size_t)r * C + c4 + k * 4);
            t[r][c4 + k*4 + 0] = f.x; t[r][c4 + k*4 + 1] = f.y;
            t[r][c4 + k*4 + 2] = f.z; t[r][c4 + k*4 + 3] = f.w;
        }
    }
    __syncthreads();
    {
        const int c = tid >> 2, r4 = (tid & 3) * 16;
        bfx8 h0, h1, l0, l1;
#pragma unroll
        for (int k = 0; k < 8; ++k) {
            float v0 = t[r4 + k][c];
            float v1 = t[r4 + 8 + k][c];
            u16 a = f2bf(v0), b = f2bf(v1);
            h0[k] = (short)a; h1[k] = (short)b;
            l0[k] = (short)f2bf(v0 - bf2f(a));
            l1[k] = (short)f2bf(v1 - bf2f(b));
        }
        u16* d = dhi + obase + (size_t)c * OS + r4;
        *(bfx8*)d = h0; *(bfx8*)(d + 8) = h1;
        if (dlo) {
            u16* d2 = dlo + obase + (size_t)c * OS + r4;
            *(bfx8*)d2 = l0; *(bfx8*)(d2 + 8) = l1;
        }
    }
}

// ---------------------------------------------------------------------------
// V transpose: v [b*T+u][E] (col h*64+s) bf16 -> vT [(b*16+h)*64+s][T=1024] bf16
// ---------------------------------------------------------------------------
__global__ __launch_bounds__(256)
void transpose_v(const u16* __restrict__ v, u16* __restrict__ vT)
{
    const int ut = blockIdx.x, h = blockIdx.y, b = blockIdx.z;
    __shared__ u16 t[64][72];
    const int tid = threadIdx.x;
    {
        const int u = tid >> 2, s4 = (tid & 3) * 16;
        const u16* src = v + ((size_t)(b * 1024 + ut * 64 + u)) * 1024 + h * 64 + s4;
        bfx8 a = *(const bfx8*)src;
        bfx8 c = *(const bfx8*)(src + 8);
#pragma unroll
        for (int k = 0; k < 8; ++k) { t[u][s4 + k] = (u16)a[k]; t[u][s4 + 8 + k] = (u16)c[k]; }
    }
    __syncthreads();
    {
        const int s = tid >> 2, u4 = (tid & 3) * 16;
        bfx8 o0, o1;
#pragma unroll
        for (int k = 0; k < 8; ++k) { o0[k] = (short)t[u4 + k][s]; o1[k] = (short)t[u4 + 8 + k][s]; }
        u16* dst = vT + ((size_t)((b * 16 + h) * 64 + s)) * 1024 + ut * 64 + u4;
        *(bfx8*)dst = o0; *(bfx8*)(dst + 8) = o1;
    }
}

// ---------------------------------------------------------------------------
// LayerNorm over E=1024, one row per block (256 thr). Output bf16 hi (+lo).
// ---------------------------------------------------------------------------
__global__ __launch_bounds__(256)
void ln_split(const float* __restrict__ x, const float* __restrict__ g,
              const float* __restrict__ be, u16* __restrict__ hhi,
              u16* __restrict__ hlo)
{
    const int row = blockIdx.x;
    const int tid = threadIdx.x;
    const float4 v = ((const float4*)(x + (size_t)row * 1024))[tid];
    float s  = v.x + v.y + v.z + v.w;
    float s2 = v.x*v.x + v.y*v.y + v.z*v.z + v.w*v.w;
#pragma unroll
    for (int m = 32; m >= 1; m >>= 1) {
        s  += __shfl_xor(s,  m, 64);
        s2 += __shfl_xor(s2, m, 64);
    }
    __shared__ float rs[4], rq[4];
    if ((tid & 63) == 0) { rs[tid >> 6] = s; rq[tid >> 6] = s2; }
    __syncthreads();
    s  = rs[0] + rs[1] + rs[2] + rs[3];
    s2 = rq[0] + rq[1] + rq[2] + rq[3];
    const float mean = s * (1.0f / 1024.0f);
    const float var  = s2 * (1.0f / 1024.0f) - mean * mean;
    const float inv  = rsqrtf(var + 1e-5f);
    const int col0 = tid * 4;
    float hv[4];
    hv[0] = (v.x - mean) * inv * g[col0+0] + be[col0+0];
    hv[1] = (v.y - mean) * inv * g[col0+1] + be[col0+1];
    hv[2] = (v.z - mean) * inv * g[col0+2] + be[col0+2];
    hv[3] = (v.w - mean) * inv * g[col0+3] + be[col0+3];
    u16v4 hb, lb;
#pragma unroll
    for (int k = 0; k < 4; ++k) {
        u16 a = f2bf(hv[k]);
        hb[k] = a;
        lb[k] = f2bf(hv[k] - bf2f(a));
    }
    *(u16v4*)(hhi + (size_t)row * 1024 + col0) = hb;
    if (hlo) *(u16v4*)(hlo + (size_t)row * 1024 + col0) = lb;
}

// ---------------------------------------------------------------------------
// GEMM: C[M,N] = A[M,K] @ Bt[N,K]^T   (m97-style: 128x128 tile, BK=32,
// 4 waves 2x2, 4x4 16x16x32 MFMA frags, global_load_lds width16 staging)
// FLAGS: 1=bias, 2=relu, 4=residual(f32, stride N), 8=f32 out (else bf16)
// ---------------------------------------------------------------------------
#define BM 128
#define BN 128
#define BKT 32

template<int FLAGS>
__global__ __launch_bounds__(256, 2)
void gemm_bt(const u16* __restrict__ A, const u16* __restrict__ Bt,
             void* __restrict__ Cout, const float* __restrict__ bias,
             const float* __restrict__ res, int M, int N, int K)
{
    __shared__ u16 As[BM * BKT];
    __shared__ u16 Bs[BN * BKT];
    const int tid  = threadIdx.x;
    const int lane = tid & 63, wave = tid >> 6;
    const int wr = wave >> 1, wc = wave & 1;
    const int li = lane & 15, lg = lane >> 4;
    const size_t m0 = (size_t)blockIdx.y * BM;
    const size_t n0 = (size_t)blockIdx.x * BN;
    f32x4 acc[4][4] = {};

    const int slot0 = tid, slot1 = tid + 256;
    const int r0 = slot0 >> 2, kc0 = (slot0 & 3) * 8;
    const int r1 = slot1 >> 2, kc1 = (slot1 & 3) * 8;

    for (int kt = 0; kt < K; kt += BKT) {
        __syncthreads();
        gl_lds16(A  + (m0 + r0) * K + kt + kc0, As + slot0 * 8);
        gl_lds16(Bt + (n0 + r0) * K + kt + kc0, Bs + slot0 * 8);
        gl_lds16(A  + (m0 + r1) * K + kt + kc1, As + slot1 * 8);
        gl_lds16(Bt + (n0 + r1) * K + kt + kc1, Bs + slot1 * 8);
        __syncthreads();
        bfx8 af[4], bfr[4];
#pragma unroll
        for (int i = 0; i < 4; ++i)
            af[i] = *(const bfx8*)&As[(wr * 64 + i * 16 + li) * BKT + lg * 8];
#pragma unroll
        for (int j = 0; j < 4; ++j)
            bfr[j] = *(const bfx8*)&Bs[(wc * 64 + j * 16 + li) * BKT + lg * 8];
#pragma unroll
        for (int i = 0; i < 4; ++i)
#pragma unroll
            for (int j = 0; j < 4; ++j)
                acc[i][j] = MFMA16(af[i], bfr[j], acc[i][j], 0, 0, 0);
    }

    float* Cf = (float*)Cout;
    u16*   Cb = (u16*)Cout;
#pragma unroll
    for (int i = 0; i < 4; ++i)
#pragma unroll
        for (int j = 0; j < 4; ++j)
#pragma unroll
            for (int r = 0; r < 4; ++r) {
                const size_t row = m0 + wr * 64 + i * 16 + lg * 4 + r;
                const size_t col = n0 + wc * 64 + j * 16 + li;
                float v = acc[i][j][r];
                if (FLAGS & 1) v += bias[col];
                if (FLAGS & 2) v = fmaxf(v, 0.0f);
                if (FLAGS & 4) v += res[row * (size_t)N + col];
                if (FLAGS & 8) Cf[row * (size_t)N + col] = v;
                else           Cb[row * (size_t)N + col] = f2bf(v);
            }
}

// ---------------------------------------------------------------------------
// Split GEMM for Q/K: C = (Ah+Al) @ (Bh+Bl)^T using 3 passes (hh, hl, lh).
// Output split into bf16 hi/lo pair.
// ---------------------------------------------------------------------------
__global__ __launch_bounds__(256, 2)
void gemm_qk(const u16* __restrict__ Ah, const u16* __restrict__ Al,
             const u16* __restrict__ Bh, const u16* __restrict__ Bl,
             u16* __restrict__ Ohi, u16* __restrict__ Olo,
             int M, int N, int K)
{
    __shared__ u16 Ahs[BM * BKT], Als[BM * BKT], Bhs[BN * BKT], Bls[BN * BKT];
    const int tid  = threadIdx.x;
    const int lane = tid & 63, wave = tid >> 6;
    const int wr = wave >> 1, wc = wave & 1;
    const int li = lane & 15, lg = lane >> 4;
    const size_t m0 = (size_t)blockIdx.y * BM;
    const size_t n0 = (size_t)blockIdx.x * BN;
    f32x4 acc[4][4] = {};

    const int slot0 = tid, slot1 = tid + 256;
    const int r0 = slot0 >> 2, kc0 = (slot0 & 3) * 8;
    const int r1 = slot1 >> 2, kc1 = (slot1 & 3) * 8;

    for (int kt = 0; kt < K; kt += BKT) {
        __syncthreads();
        gl_lds16(Ah + (m0 + r0) * K + kt + kc0, Ahs + slot0 * 8);
        gl_lds16(Al + (m0 + r0) * K + kt + kc0, Als + slot0 * 8);
        gl_lds16(Bh + (n0 + r0) * K + kt + kc0, Bhs + slot0 * 8);
        gl_lds16(Bl + (n0 + r0) * K + kt + kc0, Bls + slot0 * 8);
        gl_lds16(Ah + (m0 + r1) * K + kt + kc1, Ahs + slot1 * 8);
        gl_lds16(Al + (m0 + r1) * K + kt + kc1, Als + slot1 * 8);
        gl_lds16(Bh + (n0 + r1) * K + kt + kc1, Bhs + slot1 * 8);
        gl_lds16(Bl + (n0 + r1) * K + kt + kc1, Bls + slot1 * 8);
        __syncthreads();
        bfx8 ah[4], al4[4], bh[4], bl4[4];
#pragma unroll
        for (int i = 0; i < 4; ++i) {
            ah[i]  = *(const bfx8*)&Ahs[(wr * 64 + i * 16 + li) * BKT + lg * 8];
            al4[i] = *(const bfx8*)&Als[(wr * 64 + i * 16 + li) * BKT + lg * 8];
        }
#pragma unroll
        for (int j = 0; j < 4; ++j) {
            bh[j]  = *(const bfx8*)&Bhs[(wc * 64 + j * 16 + li) * BKT + lg * 8];
            bl4[j] = *(const bfx8*)&Bls[(wc * 64 + j * 16 + li) * BKT + lg * 8];
        }
#pragma unroll
        for (int i = 0; i < 4; ++i)
#pragma unroll
            for (int j = 0; j < 4; ++j) {
                acc[i][j] = MFMA16(ah[i],  bh[j],  acc[i][j], 0, 0, 0);
                acc[i][j] = MFMA16(ah[i],  bl4[j], acc[i][j], 0, 0, 0);
                acc[i][j] = MFMA16(al4[i], bh[j],  acc[i][j], 0, 0, 0);
            }
    }
#pragma unroll
    for (int i = 0; i < 4; ++i)
#pragma unroll
        for (int j = 0; j < 4; ++j)
#pragma unroll
            for (int r = 0; r < 4; ++r) {
                const size_t row = m0 + wr * 64 + i * 16 + lg * 4 + r;
                const size_t col = n0 + wc * 64 + j * 16 + li;
                const float v = acc[i][j][r];
                const u16 hi = f2bf(v);
                Ohi[row * (size_t)N + col] = hi;
                Olo[row * (size_t)N + col] = f2bf(v - bf2f(hi));
            }
}

// ---------------------------------------------------------------------------
// Causal flash attention. Grid (T/64, H, B), 256 thr = 4 waves.
// Wave w owns Q rows [qt*64 + w*16, +16). scores = 32 * (QhKh + QhKl + QlKh).
// Online softmax in registers; P staged via LDS (own-wave band only);
// V pre-transposed so PV B-frags are contiguous ds_read_b128.
// ---------------------------------------------------------------------------
__global__ __launch_bounds__(256, 2)
void attn(const u16* __restrict__ qhi, const u16* __restrict__ qlo,
          const u16* __restrict__ khi, const u16* __restrict__ klo,
          const u16* __restrict__ vt, u16* __restrict__ ao)
{
    const int qt = blockIdx.x, h = blockIdx.y, b = blockIdx.z;
    const int tid = threadIdx.x;
    const int wave = tid >> 6, lane = tid & 63;
    const int li = lane & 15, lg = lane >> 4;
    __shared__ u16 Vl[64 * 72];   // [s][u] padded to 72 (16B-aligned rows)
    __shared__ u16 Pl[64 * 72];   // [m][u] padded

    const size_t qrow = (size_t)b * 1024 + qt * 64 + wave * 16 + li;
    const size_t qoff = qrow * 1024 + h * 64 + lg * 8;
    const bfx8 qh0 = *(const bfx8*)(qhi + qoff);
    const bfx8 qh1 = *(const bfx8*)(qhi + qoff + 32);
    const bfx8 ql0 = *(const bfx8*)(qlo + qoff);
    const bfx8 ql1 = *(const bfx8*)(qlo + qoff + 32);

    f32x4 O[4] = {};
    float mrow[4] = {-1e30f, -1e30f, -1e30f, -1e30f};
    float lrow[4] = {0.f, 0.f, 0.f, 0.f};

    const int vs  = tid >> 2;
    const int vu4 = (tid & 3) * 16;
    const size_t vbase = ((size_t)(b * 16 + h) * 64 + vs) * 1024;

    for (int kt = 0; kt <= qt; ++kt) {
        __syncthreads();
        {   // stage transposed-V tile: Vl[s][u], u = kt*64 ..
            const u16* src = vt + vbase + kt * 64 + vu4;
            bfx8 a = *(const bfx8*)src;
            bfx8 c = *(const bfx8*)(src + 8);
            *(bfx8*)&Vl[vs * 72 + vu4]     = a;
            *(bfx8*)&Vl[vs * 72 + vu4 + 8] = c;
        }
        __syncthreads();

        // ---- scores (split bf16x3) ----
        float sv[4][4];
        const size_t kb0 = ((size_t)b * 1024 + kt * 64) * 1024 + h * 64 + lg * 8;
#pragma unroll
        for (int nf = 0; nf < 4; ++nf) {
            const size_t kb = kb0 + (size_t)(nf * 16 + li) * 1024;
            bfx8 kh0v = *(const bfx8*)(khi + kb);
            bfx8 kh1v = *(const bfx8*)(khi + kb + 32);
            bfx8 kl0v = *(const bfx8*)(klo + kb);
            bfx8 kl1v = *(const bfx8*)(klo + kb + 32);
            f32x4 a = {0.f, 0.f, 0.f, 0.f};
            a = MFMA16(qh0, kh0v, a, 0, 0, 0);
            a = MFMA16(qh1, kh1v, a, 0, 0, 0);
            a = MFMA16(qh0, kl0v, a, 0, 0, 0);
            a = MFMA16(qh1, kl1v, a, 0, 0, 0);
            a = MFMA16(ql0, kh0v, a, 0, 0, 0);
            a = MFMA16(ql1, kh1v, a, 0, 0, 0);
#pragma unroll
            for (int r = 0; r < 4; ++r) sv[nf][r] = a[r];
        }

        // ---- scale + causal mask + row max ----
        const int rowg = qt * 64 + wave * 16 + lg * 4;
        const int colg = kt * 64 + li;
        float pmax[4] = {-1e30f, -1e30f, -1e30f, -1e30f};
#pragma unroll
        for (int nf = 0; nf < 4; ++nf)
#pragma unroll
            for (int r = 0; r < 4; ++r) {
                float x2 = sv[nf][r] * 32.0f;
                if (colg + nf * 16 > rowg + r) x2 = -1e30f;
                sv[nf][r] = x2;
                pmax[r] = fmaxf(pmax[r], x2);
            }
#pragma unroll
        for (int msk = 1; msk < 16; msk <<= 1)
#pragma unroll
            for (int r = 0; r < 4; ++r)
                pmax[r] = fmaxf(pmax[r], __shfl_xor(pmax[r], msk, 64));

        // ---- online softmax update ----
        float alr[4], rsum[4];
#pragma unroll
        for (int r = 0; r < 4; ++r) {
            const float mnew = fmaxf(mrow[r], pmax[r]);
            alr[r] = __expf(mrow[r] - mnew);
            mrow[r] = mnew;
            rsum[r] = 0.0f;
        }
        float pv[4][4];
#pragma unroll
        for (int nf = 0; nf < 4; ++nf)
#pragma unroll
            for (int r = 0; r < 4; ++r) {
                const float p = __expf(sv[nf][r] - mrow[r]);
                pv[nf][r] = p;
                rsum[r] += p;
            }
#pragma unroll
        for (int msk = 1; msk < 16; msk <<= 1)
#pragma unroll
            for (int r = 0; r < 4; ++r)
                rsum[r] += __shfl_xor(rsum[r], msk, 64);
#pragma unroll
        for (int r = 0; r < 4; ++r)
            lrow[r] = lrow[r] * alr[r] + rsum[r];
#pragma unroll
        for (int nf = 0; nf < 4; ++nf)
#pragma unroll
            for (int r = 0; r < 4; ++r)
                O[nf][r] *= alr[r];

        // ---- P -> LDS (own band), then PV MFMA ----
#pragma unroll
        for (int nf = 0; nf < 4; ++nf)
#pragma unroll
            for (int r = 0; r < 4; ++r)
                Pl[(wave * 16 + lg * 4 + r) * 72 + nf * 16 + li] = f2bf(pv[nf][r]);

#pragma unroll
        for (int ku = 0; ku < 2; ++ku) {
            bfx8 pf = *(const bfx8*)&Pl[(wave * 16 + li) * 72 + ku * 32 + lg * 8];
#pragma unroll
            for (int nf = 0; nf < 4; ++nf) {
                bfx8 vf = *(const bfx8*)&Vl[(nf * 16 + li) * 72 + ku * 32 + lg * 8];
                O[nf] = MFMA16(pf, vf, O[nf], 0, 0, 0);
            }
        }
    }

    float invl[4];
#pragma unroll
    for (int r = 0; r < 4; ++r) invl[r] = 1.0f / lrow[r];
    const size_t orow = (size_t)b * 1024 + qt * 64 + wave * 16 + lg * 4;
#pragma unroll
    for (int nf = 0; nf < 4; ++nf)
#pragma unroll
        for (int r = 0; r < 4; ++r)
            ao[(orow + r) * 1024 + h * 64 + nf * 16 + li] = f2bf(O[nf][r] * invl[r]);
}

// ---------------------------------------------------------------------------
extern "C" void kernel_launch(void* const* d_in, const int* in_sizes, int n_in,
                              void* d_out, int out_size, void* d_ws, size_t ws_size,
                              hipStream_t stream)
{
    (void)in_sizes; (void)n_in; (void)out_size; (void)ws_size;
    const float* x      = (const float*)d_in[0];
    const float* wq     = (const float*)d_in[1];
    const float* wk     = (const float*)d_in[2];
    const float* wv     = (const float*)d_in[3];
    const float* w_proj = (const float*)d_in[4];
    const float* b_proj = (const float*)d_in[5];
    const float* w1     = (const float*)d_in[6];
    const float* b1     = (const float*)d_in[7];
    const float* w2     = (const float*)d_in[8];
    const float* b2     = (const float*)d_in[9];
    const float* g1     = (const float*)d_in[10];
    const float* be1    = (const float*)d_in[11];
    const float* g2     = (const float*)d_in[12];
    const float* be2    = (const float*)d_in[13];
    float* out = (float*)d_out;

    const size_t ME2 = (size_t)8192 * 1024 * 2;   // 16 MiB (M x E bf16)
    char* wsp = (char*)d_ws;
    u16* h_hi = (u16*)(wsp + 0 * ME2);            // later reused as f2 (LN2 out)
    u16* h_lo = (u16*)(wsp + 1 * ME2);            // later reused as attn-out
    u16* q_hi = (u16*)(wsp + 2 * ME2);            // later reused as FFN act (4*ME2)
    u16* q_lo = (u16*)(wsp + 3 * ME2);
    u16* k_hi = (u16*)(wsp + 4 * ME2);
    u16* k_lo = (u16*)(wsp + 5 * ME2);
    u16* v_b  = (u16*)(wsp + 6 * ME2);
    u16* vtr  = (u16*)(wsp + 7 * ME2);
    float* y  = (float*)(wsp + 8 * ME2);          // 32 MiB f32
    char* wp0 = wsp + 8 * ME2 + (size_t)8192 * 1024 * 4;
    const size_t W1M = (size_t)1024 * 1024 * 2;   // 2 MiB
    u16* wqT_hi = (u16*)(wp0 + 0 * W1M);
    u16* wqT_lo = (u16*)(wp0 + 1 * W1M);
    u16* wkT_hi = (u16*)(wp0 + 2 * W1M);
    u16* wkT_lo = (u16*)(wp0 + 3 * W1M);
    u16* wvT    = (u16*)(wp0 + 4 * W1M);
    u16* wpT    = (u16*)(wp0 + 5 * W1M);
    u16* w1T    = (u16*)(wp0 + 6 * W1M);          // 8 MiB
    u16* w2T    = (u16*)(wp0 + 6 * W1M + 4 * W1M);
    u16* f2  = h_hi;
    u16* ao  = h_lo;
    u16* act = q_hi;   // spans q_hi..k_lo = 64 MiB = 8192*4096*2

    dim3 blk(256);

    // weight repacks (transpose to [N][K] bf16; hi/lo split for wq, wk)
    transpose_split<<<dim3(1, 16, 16), blk, 0, stream>>>(wq, wqT_hi, wqT_lo, 64, 1024, (size_t)65536, (size_t)65536);
    transpose_split<<<dim3(1, 16, 16), blk, 0, stream>>>(wk, wkT_hi, wkT_lo, 64, 1024, (size_t)65536, (size_t)65536);
    transpose_split<<<dim3(1, 16, 16), blk, 0, stream>>>(wv, wvT, nullptr, 64, 1024, (size_t)65536, (size_t)65536);
    transpose_split<<<dim3(16, 16, 1), blk, 0, stream>>>(w_proj, wpT, nullptr, 1024, 1024, 0, 0);
    transpose_split<<<dim3(64, 16, 1), blk, 0, stream>>>(w1, w1T, nullptr, 4096, 1024, 0, 0);
    transpose_split<<<dim3(16, 64, 1), blk, 0, stream>>>(w2, w2T, nullptr, 1024, 4096, 0, 0);

    // LN1 (split output)
    ln_split<<<8192, blk, 0, stream>>>(x, g1, be1, h_hi, h_lo);

    // Q, K (bf16x3 split GEMM), V (plain)
    gemm_qk<<<dim3(8, 64), blk, 0, stream>>>(h_hi, h_lo, wqT_hi, wqT_lo, q_hi, q_lo, 8192, 1024, 1024);
    gemm_qk<<<dim3(8, 64), blk, 0, stream>>>(h_hi, h_lo, wkT_hi, wkT_lo, k_hi, k_lo, 8192, 1024, 1024);
    gemm_bt<0><<<dim3(8, 64), blk, 0, stream>>>(h_hi, wvT, v_b, nullptr, nullptr, 8192, 1024, 1024);
    transpose_v<<<dim3(16, 16, 8), blk, 0, stream>>>(v_b, vtr);

    // attention
    attn<<<dim3(16, 16, 8), blk, 0, stream>>>(q_hi, q_lo, k_hi, k_lo, vtr, ao);

    // proj + bias + residual(x) -> y (f32)
    gemm_bt<1 | 4 | 8><<<dim3(8, 64), blk, 0, stream>>>(ao, wpT, y, b_proj, x, 8192, 1024, 1024);

    // LN2
    ln_split<<<8192, blk, 0, stream>>>(y, g2, be2, f2, nullptr);

    // FFN
    gemm_bt<1 | 2><<<dim3(32, 64), blk, 0, stream>>>(f2, w1T, act, b1, nullptr, 8192, 4096, 1024);
    gemm_bt<1 | 4 | 8><<<dim3(8, 64), blk, 0, stream>>>(act, w2T, out, b2, y, 8192, 1024, 4096);
}

// Round 2
// 554.993 us; speedup vs baseline: 1.2151x; 1.2151x over previous
//
#include <hip/hip_runtime.h>

// ---------------------------------------------------------------------------
// TransformerBlock: B=8, T=1024, E=1024, H=16, HS=64, FF=4096
// bf16 MFMA (16x16x32) everywhere; bf16x3 split (hi/lo) on LN1->Q,K and QK^T
// because the reference scales scores by sqrt(T)=32 (near-one-hot softmax).
// R2: attn rewritten as 2-phase pipelined kernel (LDS-staged swizzled K,
// counted vmcnt, raw barriers, V->regs, XCD-chunked + qt-reversed schedule).
// ---------------------------------------------------------------------------

typedef unsigned short u16;
typedef __attribute__((ext_vector_type(8))) short  bfx8;
typedef __attribute__((ext_vector_type(4))) float  f32x4;
typedef __attribute__((ext_vector_type(4))) unsigned short u16v4;

#define MFMA16 __builtin_amdgcn_mfma_f32_16x16x32_bf16

__device__ __forceinline__ u16 f2bf(float f) {
    union { float f; unsigned u; } c; c.f = f;
    unsigned r = c.u + 0x7fffu + ((c.u >> 16) & 1u);
    return (u16)(r >> 16);
}
__device__ __forceinline__ float bf2f(u16 b) {
    union { unsigned u; float f; } c; c.u = ((unsigned)b) << 16; return c.f;
}

__device__ __forceinline__ void gl_lds16(const void* g, void* l) {
    void* gg = (void*)g;
    __builtin_amdgcn_global_load_lds(
        (__attribute__((address_space(1))) void*)gg,
        (__attribute__((address_space(3))) void*)l,
        16, 0, 0);
}

// ---------------------------------------------------------------------------
// Generic 64x64-tiled transpose: src f32 [R][C] (row-major) -> dst bf16 [C][R]
// (dst row stride OS). Optional hi/lo split. Batched via blockIdx.z.
// ---------------------------------------------------------------------------
__global__ __launch_bounds__(256)
void transpose_split(const float* __restrict__ src, u16* __restrict__ dhi,
                     u16* __restrict__ dlo, int C, int OS,
                     size_t inBS, size_t outBS)
{
    __shared__ float t[64][65];
    const int tid = threadIdx.x;
    const float* s = src + (size_t)blockIdx.z * inBS
                   + ((size_t)blockIdx.y * 64) * C + (size_t)blockIdx.x * 64;
    const size_t obase = (size_t)blockIdx.z * outBS
                       + ((size_t)blockIdx.x * 64) * OS + (size_t)blockIdx.y * 64;
    {
        const int r = tid >> 2, c4 = (tid & 3) * 16;
#pragma unroll
        for (int k = 0; k < 4; ++k) {
            float4 f = *(const float4*)(s + (size_t)r * C + c4 + k * 4);
            t[r][c4 + k*4 + 0] = f.x; t[r][c4 + k*4 + 1] = f.y;
            t[r][c4 + k*4 + 2] = f.z; t[r][c4 + k*4 + 3] = f.w;
        }
    }
    __syncthreads();
    {
        const int c = tid >> 2, r4 = (tid & 3) * 16;
        bfx8 h0, h1, l0, l1;
#pragma unroll
        for (int k = 0; k < 8; ++k) {
            float v0 = t[r4 + k][c];
            float v1 = t[r4 + 8 + k][c];
            u16 a = f2bf(v0), b = f2bf(v1);
            h0[k] = (short)a; h1[k] = (short)b;
            l0[k] = (short)f2bf(v0 - bf2f(a));
            l1[k] = (short)f2bf(v1 - bf2f(b));
        }
        u16* d = dhi + obase + (size_t)c * OS + r4;
        *(bfx8*)d = h0; *(bfx8*)(d + 8) = h1;
        if (dlo) {
            u16* d2 = dlo + obase + (size_t)c * OS + r4;
            *(bfx8*)d2 = l0; *(bfx8*)(d2 + 8) = l1;
        }
    }
}

// ---------------------------------------------------------------------------
// V transpose: v [b*T+u][E] (col h*64+s) bf16 -> vT [(b*16+h)*64+s][T=1024] bf16
// ---------------------------------------------------------------------------
__global__ __launch_bounds__(256)
void transpose_v(const u16* __restrict__ v, u16* __restrict__ vT)
{
    const int ut = blockIdx.x, h = blockIdx.y, b = blockIdx.z;
    __shared__ u16 t[64][72];
    const int tid = threadIdx.x;
    {
        const int u = tid >> 2, s4 = (tid & 3) * 16;
        const u16* src = v + ((size_t)(b * 1024 + ut * 64 + u)) * 1024 + h * 64 + s4;
        bfx8 a = *(const bfx8*)src;
        bfx8 c = *(const bfx8*)(src + 8);
#pragma unroll
        for (int k = 0; k < 8; ++k) { t[u][s4 + k] = (u16)a[k]; t[u][s4 + 8 + k] = (u16)c[k]; }
    }
    __syncthreads();
    {
        const int s = tid >> 2, u4 = (tid & 3) * 16;
        bfx8 o0, o1;
#pragma unroll
        for (int k = 0; k < 8; ++k) { o0[k] = (short)t[u4 + k][s]; o1[k] = (short)t[u4 + 8 + k][s]; }
        u16* dst = vT + ((size_t)((b * 16 + h) * 64 + s)) * 1024 + ut * 64 + u4;
        *(bfx8*)dst = o0; *(bfx8*)(dst + 8) = o1;
    }
}

// ---------------------------------------------------------------------------
// LayerNorm over E=1024, one row per block (256 thr). Output bf16 hi (+lo).
// ---------------------------------------------------------------------------
__global__ __launch_bounds__(256)
void ln_split(const float* __restrict__ x, const float* __restrict__ g,
              const float* __restrict__ be, u16* __restrict__ hhi,
              u16* __restrict__ hlo)
{
    const int row = blockIdx.x;
    const int tid = threadIdx.x;
    const float4 v = ((const float4*)(x + (size_t)row * 1024))[tid];
    float s  = v.x + v.y + v.z + v.w;
    float s2 = v.x*v.x + v.y*v.y + v.z*v.z + v.w*v.w;
#pragma unroll
    for (int m = 32; m >= 1; m >>= 1) {
        s  += __shfl_xor(s,  m, 64);
        s2 += __shfl_xor(s2, m, 64);
    }
    __shared__ float rs[4], rq[4];
    if ((tid & 63) == 0) { rs[tid >> 6] = s; rq[tid >> 6] = s2; }
    __syncthreads();
    s  = rs[0] + rs[1] + rs[2] + rs[3];
    s2 = rq[0] + rq[1] + rq[2] + rq[3];
    const float mean = s * (1.0f / 1024.0f);
    const float var  = s2 * (1.0f / 1024.0f) - mean * mean;
    const float inv  = rsqrtf(var + 1e-5f);
    const int col0 = tid * 4;
    float hv[4];
    hv[0] = (v.x - mean) * inv * g[col0+0] + be[col0+0];
    hv[1] = (v.y - mean) * inv * g[col0+1] + be[col0+1];
    hv[2] = (v.z - mean) * inv * g[col0+2] + be[col0+2];
    hv[3] = (v.w - mean) * inv * g[col0+3] + be[col0+3];
    u16v4 hb, lb;
#pragma unroll
    for (int k = 0; k < 4; ++k) {
        u16 a = f2bf(hv[k]);
        hb[k] = a;
        lb[k] = f2bf(hv[k] - bf2f(a));
    }
    *(u16v4*)(hhi + (size_t)row * 1024 + col0) = hb;
    if (hlo) *(u16v4*)(hlo + (size_t)row * 1024 + col0) = lb;
}

// ---------------------------------------------------------------------------
// GEMM: C[M,N] = A[M,K] @ Bt[N,K]^T   (m97-style: 128x128 tile, BK=32,
// 4 waves 2x2, 4x4 16x16x32 MFMA frags, global_load_lds width16 staging)
// FLAGS: 1=bias, 2=relu, 4=residual(f32, stride N), 8=f32 out (else bf16)
// ---------------------------------------------------------------------------
#define BM 128
#define BN 128
#define BKT 32

template<int FLAGS>
__global__ __launch_bounds__(256, 2)
void gemm_bt(const u16* __restrict__ A, const u16* __restrict__ Bt,
             void* __restrict__ Cout, const float* __restrict__ bias,
             const float* __restrict__ res, int M, int N, int K)
{
    __shared__ u16 As[BM * BKT];
    __shared__ u16 Bs[BN * BKT];
    const int tid  = threadIdx.x;
    const int lane = tid & 63, wave = tid >> 6;
    const int wr = wave >> 1, wc = wave & 1;
    const int li = lane & 15, lg = lane >> 4;
    const size_t m0 = (size_t)blockIdx.y * BM;
    const size_t n0 = (size_t)blockIdx.x * BN;
    f32x4 acc[4][4] = {};

    const int slot0 = tid, slot1 = tid + 256;
    const int r0 = slot0 >> 2, kc0 = (slot0 & 3) * 8;
    const int r1 = slot1 >> 2, kc1 = (slot1 & 3) * 8;

    for (int kt = 0; kt < K; kt += BKT) {
        __syncthreads();
        gl_lds16(A  + (m0 + r0) * K + kt + kc0, As + slot0 * 8);
        gl_lds16(Bt + (n0 + r0) * K + kt + kc0, Bs + slot0 * 8);
        gl_lds16(A  + (m0 + r1) * K + kt + kc1, As + slot1 * 8);
        gl_lds16(Bt + (n0 + r1) * K + kt + kc1, Bs + slot1 * 8);
        __syncthreads();
        bfx8 af[4], bfr[4];
#pragma unroll
        for (int i = 0; i < 4; ++i)
            af[i] = *(const bfx8*)&As[(wr * 64 + i * 16 + li) * BKT + lg * 8];
#pragma unroll
        for (int j = 0; j < 4; ++j)
            bfr[j] = *(const bfx8*)&Bs[(wc * 64 + j * 16 + li) * BKT + lg * 8];
#pragma unroll
        for (int i = 0; i < 4; ++i)
#pragma unroll
            for (int j = 0; j < 4; ++j)
                acc[i][j] = MFMA16(af[i], bfr[j], acc[i][j], 0, 0, 0);
    }

    float* Cf = (float*)Cout;
    u16*   Cb = (u16*)Cout;
#pragma unroll
    for (int i = 0; i < 4; ++i)
#pragma unroll
        for (int j = 0; j < 4; ++j)
#pragma unroll
            for (int r = 0; r < 4; ++r) {
                const size_t row = m0 + wr * 64 + i * 16 + lg * 4 + r;
                const size_t col = n0 + wc * 64 + j * 16 + li;
                float v = acc[i][j][r];
                if (FLAGS & 1) v += bias[col];
                if (FLAGS & 2) v = fmaxf(v, 0.0f);
                if (FLAGS & 4) v += res[row * (size_t)N + col];
                if (FLAGS & 8) Cf[row * (size_t)N + col] = v;
                else           Cb[row * (size_t)N + col] = f2bf(v);
            }
}

// ---------------------------------------------------------------------------
// Split GEMM for Q/K: C = (Ah+Al) @ (Bh+Bl)^T using 3 passes (hh, hl, lh).
// Output split into bf16 hi/lo pair.
// ---------------------------------------------------------------------------
__global__ __launch_bounds__(256, 2)
void gemm_qk(const u16* __restrict__ Ah, const u16* __restrict__ Al,
             const u16* __restrict__ Bh, const u16* __restrict__ Bl,
             u16* __restrict__ Ohi, u16* __restrict__ Olo,
             int M, int N, int K)
{
    __shared__ u16 Ahs[BM * BKT], Als[BM * BKT], Bhs[BN * BKT], Bls[BN * BKT];
    const int tid  = threadIdx.x;
    const int lane = tid & 63, wave = tid >> 6;
    const int wr = wave >> 1, wc = wave & 1;
    const int li = lane & 15, lg = lane >> 4;
    const size_t m0 = (size_t)blockIdx.y * BM;
    const size_t n0 = (size_t)blockIdx.x * BN;
    f32x4 acc[4][4] = {};

    const int slot0 = tid, slot1 = tid + 256;
    const int r0 = slot0 >> 2, kc0 = (slot0 & 3) * 8;
    const int r1 = slot1 >> 2, kc1 = (slot1 & 3) * 8;

    for (int kt = 0; kt < K; kt += BKT) {
        __syncthreads();
        gl_lds16(Ah + (m0 + r0) * K + kt + kc0, Ahs + slot0 * 8);
        gl_lds16(Al + (m0 + r0) * K + kt + kc0, Als + slot0 * 8);
        gl_lds16(Bh + (n0 + r0) * K + kt + kc0, Bhs + slot0 * 8);
        gl_lds16(Bl + (n0 + r0) * K + kt + kc0, Bls + slot0 * 8);
        gl_lds16(Ah + (m0 + r1) * K + kt + kc1, Ahs + slot1 * 8);
        gl_lds16(Al + (m0 + r1) * K + kt + kc1, Als + slot1 * 8);
        gl_lds16(Bh + (n0 + r1) * K + kt + kc1, Bhs + slot1 * 8);
        gl_lds16(Bl + (n0 + r1) * K + kt + kc1, Bls + slot1 * 8);
        __syncthreads();
        bfx8 ah[4], al4[4], bh[4], bl4[4];
#pragma unroll
        for (int i = 0; i < 4; ++i) {
            ah[i]  = *(const bfx8*)&Ahs[(wr * 64 + i * 16 + li) * BKT + lg * 8];
            al4[i] = *(const bfx8*)&Als[(wr * 64 + i * 16 + li) * BKT + lg * 8];
        }
#pragma unroll
        for (int j = 0; j < 4; ++j) {
            bh[j]  = *(const bfx8*)&Bhs[(wc * 64 + j * 16 + li) * BKT + lg * 8];
            bl4[j] = *(const bfx8*)&Bls[(wc * 64 + j * 16 + li) * BKT + lg * 8];
        }
#pragma unroll
        for (int i = 0; i < 4; ++i)
#pragma unroll
            for (int j = 0; j < 4; ++j) {
                acc[i][j] = MFMA16(ah[i],  bh[j],  acc[i][j], 0, 0, 0);
                acc[i][j] = MFMA16(ah[i],  bl4[j], acc[i][j], 0, 0, 0);
                acc[i][j] = MFMA16(al4[i], bh[j],  acc[i][j], 0, 0, 0);
            }
    }
#pragma unroll
    for (int i = 0; i < 4; ++i)
#pragma unroll
        for (int j = 0; j < 4; ++j)
#pragma unroll
            for (int r = 0; r < 4; ++r) {
                const size_t row = m0 + wr * 64 + i * 16 + lg * 4 + r;
                const size_t col = n0 + wc * 64 + j * 16 + li;
                const float v = acc[i][j][r];
                const u16 hi = f2bf(v);
                Ohi[row * (size_t)N + col] = hi;
                Olo[row * (size_t)N + col] = f2bf(v - bf2f(hi));
            }
}

// ---------------------------------------------------------------------------
// Causal flash attention, 2-phase pipelined.
// 1-D grid of 2048 blocks, XCD-chunked (each XCD ~ one batch b) and
// qt-reversed (long blocks first). 256 thr = 4 waves; wave w owns Q rows
// [qt*64 + w*16, +16).
// K hi/lo double-buffered in LDS via global_load_lds with XOR-swizzle
// (byte ^= (row&7)<<4, applied on the pre-swizzled global source and on the
// ds_read address). Counted vmcnt (12 = 8 V-reg loads + 4 stage loads) so
// next-tile staging stays in flight across barriers. V fragments go
// global->reg at iter top, consumed at iter end (PV).
// ---------------------------------------------------------------------------
__global__ __launch_bounds__(256, 3)
void attn(const u16* __restrict__ qhi, const u16* __restrict__ qlo,
          const u16* __restrict__ khi, const u16* __restrict__ klo,
          const u16* __restrict__ vt, u16* __restrict__ ao)
{
    // decode XCD-chunked, qt-reversed schedule (2048 = 8 XCD chunks of 256)
    const int id  = blockIdx.x;
    const int swz = (id & 7) * 256 + (id >> 3);
    const int qt  = 15 - (swz & 15);
    const int h   = (swz >> 4) & 15;
    const int b   = swz >> 8;

    const int tid = threadIdx.x;
    const int wave = tid >> 6, lane = tid & 63;
    const int li = lane & 15, lg = lane >> 4;

    __shared__ u16 KsHi[2][4096];   // [buf][row 0..63][col 0..63] swizzled
    __shared__ u16 KsLo[2][4096];
    __shared__ u16 Pl[64 * 72];

    const size_t qrow = (size_t)b * 1024 + qt * 64 + wave * 16 + li;
    const size_t qoff = qrow * 1024 + h * 64 + lg * 8;
    const bfx8 qh0 = *(const bfx8*)(qhi + qoff);
    const bfx8 qh1 = *(const bfx8*)(qhi + qoff + 32);
    const bfx8 ql0 = *(const bfx8*)(qlo + qoff);
    const bfx8 ql1 = *(const bfx8*)(qlo + qoff + 32);

    f32x4 O[4] = {};
    float mrow[4] = {-1e30f, -1e30f, -1e30f, -1e30f};
    float lrow[4] = {0.f, 0.f, 0.f, 0.f};

    const u16* kh_base = khi + ((size_t)b * 1024) * 1024 + h * 64;
    const u16* kl_base = klo + ((size_t)b * 1024) * 1024 + h * 64;
    const u16* v_base  = vt + ((size_t)(b * 16 + h) * 64) * 1024;

    // staging lambda: 4 gl_lds16 per thread (2 sites x {hi,lo})
    auto stageK = [&](int kt, int bufIdx) {
#pragma unroll
        for (int site = 0; site < 2; ++site) {
            const int s = tid + site * 256;          // 0..511 slots of 16B
            const int r = s >> 3;
            const int cb = (((s & 7) << 4) ^ ((r & 7) << 4));  // bytes in row
            const size_t go = ((size_t)(kt * 64 + r)) * 1024;  // elements
            gl_lds16((const char*)(kh_base + go) + cb, (char*)&KsHi[bufIdx][0] + s * 16);
            gl_lds16((const char*)(kl_base + go) + cb, (char*)&KsLo[bufIdx][0] + s * 16);
        }
    };

    const int rswz = (li & 7) << 4;   // read-side XOR swizzle (bytes)

    stageK(0, 0);

    for (int kt = 0; kt <= qt; ++kt) {
        const int cur = kt & 1;

        // ---- issue V(kt) register loads (consumed in PV at iter end) ----
        bfx8 vld[2][4];
#pragma unroll
        for (int nf = 0; nf < 4; ++nf) {
            const u16* vr = v_base + ((size_t)(nf * 16 + li)) * 1024 + kt * 64 + lg * 8;
            vld[0][nf] = *(const bfx8*)vr;
            vld[1][nf] = *(const bfx8*)(vr + 32);
        }

        // ---- issue next-tile staging, wait for current tile staged ----
        if (kt < qt) {
            stageK(kt + 1, cur ^ 1);
            asm volatile("s_waitcnt vmcnt(12)" ::: "memory");
        } else {
            asm volatile("s_waitcnt vmcnt(8)" ::: "memory");
        }
        __builtin_amdgcn_sched_barrier(0);
        __builtin_amdgcn_s_barrier();          // barrier A: tile kt staged
        __builtin_amdgcn_sched_barrier(0);

        // ---- scores (split bf16x3) from LDS ----
        float sv[4][4];
        const char* khc = (const char*)&KsHi[cur][0];
        const char* klc = (const char*)&KsLo[cur][0];
#pragma unroll
        for (int nf = 0; nf < 4; ++nf) {
            const int rb = (nf * 16 + li) * 128;
            bfx8 kh0v = *(const bfx8*)(khc + rb + (((lg * 16) + 0 ) ^ rswz));
            bfx8 kh1v = *(const bfx8*)(khc + rb + (((lg * 16) + 64) ^ rswz));
            bfx8 kl0v = *(const bfx8*)(klc + rb + (((lg * 16) + 0 ) ^ rswz));
            bfx8 kl1v = *(const bfx8*)(klc + rb + (((lg * 16) + 64) ^ rswz));
            f32x4 a = {0.f, 0.f, 0.f, 0.f};
            a = MFMA16(qh0, kh0v, a, 0, 0, 0);
            a = MFMA16(qh1, kh1v, a, 0, 0, 0);
            a = MFMA16(qh0, kl0v, a, 0, 0, 0);
            a = MFMA16(qh1, kl1v, a, 0, 0, 0);
            a = MFMA16(ql0, kh0v, a, 0, 0, 0);
            a = MFMA16(ql1, kh1v, a, 0, 0, 0);
#pragma unroll
            for (int r = 0; r < 4; ++r) sv[nf][r] = a[r];
        }

        // barrier B: all waves done reading buf[cur] -> safe to re-stage it
        asm volatile("s_waitcnt lgkmcnt(0)" ::: "memory");
        __builtin_amdgcn_sched_barrier(0);
        __builtin_amdgcn_s_barrier();
        __builtin_amdgcn_sched_barrier(0);

        // ---- scale + causal mask + row max ----
        const int rowg = qt * 64 + wave * 16 + lg * 4;
        const int colg = kt * 64 + li;
        float pmax[4] = {-1e30f, -1e30f, -1e30f, -1e30f};
#pragma unroll
        for (int nf = 0; nf < 4; ++nf)
#pragma unroll
            for (int r = 0; r < 4; ++r) {
                float x2 = sv[nf][r] * 32.0f;
                if (colg + nf * 16 > rowg + r) x2 = -1e30f;
                sv[nf][r] = x2;
                pmax[r] = fmaxf(pmax[r], x2);
            }
#pragma unroll
        for (int msk = 1; msk < 16; msk <<= 1)
#pragma unroll
            for (int r = 0; r < 4; ++r)
                pmax[r] = fmaxf(pmax[r], __shfl_xor(pmax[r], msk, 64));

        // ---- online softmax update ----
        float alr[4], rsum[4];
#pragma unroll
        for (int r = 0; r < 4; ++r) {
            const float mnew = fmaxf(mrow[r], pmax[r]);
            alr[r] = __expf(mrow[r] - mnew);
            mrow[r] = mnew;
            rsum[r] = 0.0f;
        }
        float pv[4][4];
#pragma unroll
        for (int nf = 0; nf < 4; ++nf)
#pragma unroll
            for (int r = 0; r < 4; ++r) {
                const float p = __expf(sv[nf][r] - mrow[r]);
                pv[nf][r] = p;
                rsum[r] += p;
            }
#pragma unroll
        for (int msk = 1; msk < 16; msk <<= 1)
#pragma unroll
            for (int r = 0; r < 4; ++r)
                rsum[r] += __shfl_xor(rsum[r], msk, 64);
#pragma unroll
        for (int r = 0; r < 4; ++r)
            lrow[r] = lrow[r] * alr[r] + rsum[r];
#pragma unroll
        for (int nf = 0; nf < 4; ++nf)
#pragma unroll
            for (int r = 0; r < 4; ++r)
                O[nf][r] *= alr[r];

        // ---- P -> LDS (own-wave band only; no barrier needed) ----
#pragma unroll
        for (int nf = 0; nf < 4; ++nf)
#pragma unroll
            for (int r = 0; r < 4; ++r)
                Pl[(wave * 16 + lg * 4 + r) * 72 + nf * 16 + li] = f2bf(pv[nf][r]);

        // ---- PV MFMA (V from registers) ----
#pragma unroll
        for (int ku = 0; ku < 2; ++ku) {
            bfx8 pf = *(const bfx8*)&Pl[(wave * 16 + li) * 72 + ku * 32 + lg * 8];
#pragma unroll
            for (int nf = 0; nf < 4; ++nf)
                O[nf] = MFMA16(pf, vld[ku][nf], O[nf], 0, 0, 0);
        }
    }

    float invl[4];
#pragma unroll
    for (int r = 0; r < 4; ++r) invl[r] = 1.0f / lrow[r];
    const size_t orow = (size_t)b * 1024 + qt * 64 + wave * 16 + lg * 4;
#pragma unroll
    for (int nf = 0; nf < 4; ++nf)
#pragma unroll
        for (int r = 0; r < 4; ++r)
            ao[(orow + r) * 1024 + h * 64 + nf * 16 + li] = f2bf(O[nf][r] * invl[r]);
}

// ---------------------------------------------------------------------------
extern "C" void kernel_launch(void* const* d_in, const int* in_sizes, int n_in,
                              void* d_out, int out_size, void* d_ws, size_t ws_size,
                              hipStream_t stream)
{
    (void)in_sizes; (void)n_in; (void)out_size; (void)ws_size;
    const float* x      = (const float*)d_in[0];
    const float* wq     = (const float*)d_in[1];
    const float* wk     = (const float*)d_in[2];
    const float* wv     = (const float*)d_in[3];
    const float* w_proj = (const float*)d_in[4];
    const float* b_proj = (const float*)d_in[5];
    const float* w1     = (const float*)d_in[6];
    const float* b1     = (const float*)d_in[7];
    const float* w2     = (const float*)d_in[8];
    const float* b2     = (const float*)d_in[9];
    const float* g1     = (const float*)d_in[10];
    const float* be1    = (const float*)d_in[11];
    const float* g2     = (const float*)d_in[12];
    const float* be2    = (const float*)d_in[13];
    float* out = (float*)d_out;

    const size_t ME2 = (size_t)8192 * 1024 * 2;   // 16 MiB (M x E bf16)
    char* wsp = (char*)d_ws;
    u16* h_hi = (u16*)(wsp + 0 * ME2);            // later reused as f2 (LN2 out)
    u16* h_lo = (u16*)(wsp + 1 * ME2);            // later reused as attn-out
    u16* q_hi = (u16*)(wsp + 2 * ME2);            // later reused as FFN act (4*ME2)
    u16* q_lo = (u16*)(wsp + 3 * ME2);
    u16* k_hi = (u16*)(wsp + 4 * ME2);
    u16* k_lo = (u16*)(wsp + 5 * ME2);
    u16* v_b  = (u16*)(wsp + 6 * ME2);
    u16* vtr  = (u16*)(wsp + 7 * ME2);
    float* y  = (float*)(wsp + 8 * ME2);          // 32 MiB f32
    char* wp0 = wsp + 8 * ME2 + (size_t)8192 * 1024 * 4;
    const size_t W1M = (size_t)1024 * 1024 * 2;   // 2 MiB
    u16* wqT_hi = (u16*)(wp0 + 0 * W1M);
    u16* wqT_lo = (u16*)(wp0 + 1 * W1M);
    u16* wkT_hi = (u16*)(wp0 + 2 * W1M);
    u16* wkT_lo = (u16*)(wp0 + 3 * W1M);
    u16* wvT    = (u16*)(wp0 + 4 * W1M);
    u16* wpT    = (u16*)(wp0 + 5 * W1M);
    u16* w1T    = (u16*)(wp0 + 6 * W1M);          // 8 MiB
    u16* w2T    = (u16*)(wp0 + 6 * W1M + 4 * W1M);
    u16* f2  = h_hi;
    u16* ao  = h_lo;
    u16* act = q_hi;   // spans q_hi..k_lo = 64 MiB = 8192*4096*2

    dim3 blk(256);

    // weight repacks (transpose to [N][K] bf16; hi/lo split for wq, wk)
    transpose_split<<<dim3(1, 16, 16), blk, 0, stream>>>(wq, wqT_hi, wqT_lo, 64, 1024, (size_t)65536, (size_t)65536);
    transpose_split<<<dim3(1, 16, 16), blk, 0, stream>>>(wk, wkT_hi, wkT_lo, 64, 1024, (size_t)65536, (size_t)65536);
    transpose_split<<<dim3(1, 16, 16), blk, 0, stream>>>(wv, wvT, nullptr, 64, 1024, (size_t)65536, (size_t)65536);
    transpose_split<<<dim3(16, 16, 1), blk, 0, stream>>>(w_proj, wpT, nullptr, 1024, 1024, 0, 0);
    transpose_split<<<dim3(64, 16, 1), blk, 0, stream>>>(w1, w1T, nullptr, 4096, 1024, 0, 0);
    transpose_split<<<dim3(16, 64, 1), blk, 0, stream>>>(w2, w2T, nullptr, 1024, 4096, 0, 0);

    // LN1 (split output)
    ln_split<<<8192, blk, 0, stream>>>(x, g1, be1, h_hi, h_lo);

    // Q, K (bf16x3 split GEMM), V (plain)
    gemm_qk<<<dim3(8, 64), blk, 0, stream>>>(h_hi, h_lo, wqT_hi, wqT_lo, q_hi, q_lo, 8192, 1024, 1024);
    gemm_qk<<<dim3(8, 64), blk, 0, stream>>>(h_hi, h_lo, wkT_hi, wkT_lo, k_hi, k_lo, 8192, 1024, 1024);
    gemm_bt<0><<<dim3(8, 64), blk, 0, stream>>>(h_hi, wvT, v_b, nullptr, nullptr, 8192, 1024, 1024);
    transpose_v<<<dim3(16, 16, 8), blk, 0, stream>>>(v_b, vtr);

    // attention (1-D grid, XCD-chunked + qt-reversed inside the kernel)
    attn<<<dim3(2048), blk, 0, stream>>>(q_hi, q_lo, k_hi, k_lo, vtr, ao);

    // proj + bias + residual(x) -> y (f32)
    gemm_bt<1 | 4 | 8><<<dim3(8, 64), blk, 0, stream>>>(ao, wpT, y, b_proj, x, 8192, 1024, 1024);

    // LN2
    ln_split<<<8192, blk, 0, stream>>>(y, g2, be2, f2, nullptr);

    // FFN
    gemm_bt<1 | 2><<<dim3(32, 64), blk, 0, stream>>>(f2, w1T, act, b1, nullptr, 8192, 4096, 1024);
    gemm_bt<1 | 4 | 8><<<dim3(8, 64), blk, 0, stream>>>(act, w2T, out, b2, y, 8192, 1024, 4096);
}

// Round 3
// 546.828 us; speedup vs baseline: 1.2333x; 1.0149x over previous
//
#include <hip/hip_runtime.h>

// ---------------------------------------------------------------------------
// TransformerBlock: B=8, T=1024, E=1024, H=16, HS=64, FF=4096
// bf16 MFMA (16x16x32) everywhere; bf16x3 split (hi/lo) on LN1->Q,K and QK^T
// because the reference scales scores by sqrt(T)=32 (near-one-hot softmax).
// R3: ffn1 moved to 256^2 8-phase schedule (T2 swizzle + T4 counted vmcnt +
// T5 setprio); attn exp -> exp2 domain (drops one v_mul per exp).
// ---------------------------------------------------------------------------

typedef unsigned short u16;
typedef __attribute__((ext_vector_type(8))) short  bfx8;
typedef __attribute__((ext_vector_type(4))) float  f32x4;
typedef __attribute__((ext_vector_type(4))) unsigned short u16v4;

#define MFMA16 __builtin_amdgcn_mfma_f32_16x16x32_bf16

__device__ __forceinline__ u16 f2bf(float f) {
    union { float f; unsigned u; } c; c.f = f;
    unsigned r = c.u + 0x7fffu + ((c.u >> 16) & 1u);
    return (u16)(r >> 16);
}
__device__ __forceinline__ float bf2f(u16 b) {
    union { unsigned u; float f; } c; c.u = ((unsigned)b) << 16; return c.f;
}
__device__ __forceinline__ float exp2_fast(float x) {
    float r; asm("v_exp_f32 %0, %1" : "=v"(r) : "v"(x)); return r;
}

__device__ __forceinline__ void gl_lds16(const void* g, void* l) {
    void* gg = (void*)g;
    __builtin_amdgcn_global_load_lds(
        (__attribute__((address_space(1))) void*)gg,
        (__attribute__((address_space(3))) void*)l,
        16, 0, 0);
}

// ---------------------------------------------------------------------------
// Generic 64x64-tiled transpose: src f32 [R][C] (row-major) -> dst bf16 [C][R]
// ---------------------------------------------------------------------------
__global__ __launch_bounds__(256)
void transpose_split(const float* __restrict__ src, u16* __restrict__ dhi,
                     u16* __restrict__ dlo, int C, int OS,
                     size_t inBS, size_t outBS)
{
    __shared__ float t[64][65];
    const int tid = threadIdx.x;
    const float* s = src + (size_t)blockIdx.z * inBS
                   + ((size_t)blockIdx.y * 64) * C + (size_t)blockIdx.x * 64;
    const size_t obase = (size_t)blockIdx.z * outBS
                       + ((size_t)blockIdx.x * 64) * OS + (size_t)blockIdx.y * 64;
    {
        const int r = tid >> 2, c4 = (tid & 3) * 16;
#pragma unroll
        for (int k = 0; k < 4; ++k) {
            float4 f = *(const float4*)(s + (size_t)r * C + c4 + k * 4);
            t[r][c4 + k*4 + 0] = f.x; t[r][c4 + k*4 + 1] = f.y;
            t[r][c4 + k*4 + 2] = f.z; t[r][c4 + k*4 + 3] = f.w;
        }
    }
    __syncthreads();
    {
        const int c = tid >> 2, r4 = (tid & 3) * 16;
        bfx8 h0, h1, l0, l1;
#pragma unroll
        for (int k = 0; k < 8; ++k) {
            float v0 = t[r4 + k][c];
            float v1 = t[r4 + 8 + k][c];
            u16 a = f2bf(v0), b = f2bf(v1);
            h0[k] = (short)a; h1[k] = (short)b;
            l0[k] = (short)f2bf(v0 - bf2f(a));
            l1[k] = (short)f2bf(v1 - bf2f(b));
        }
        u16* d = dhi + obase + (size_t)c * OS + r4;
        *(bfx8*)d = h0; *(bfx8*)(d + 8) = h1;
        if (dlo) {
            u16* d2 = dlo + obase + (size_t)c * OS + r4;
            *(bfx8*)d2 = l0; *(bfx8*)(d2 + 8) = l1;
        }
    }
}

// ---------------------------------------------------------------------------
// V transpose: v [b*T+u][E] (col h*64+s) bf16 -> vT [(b*16+h)*64+s][T=1024]
// ---------------------------------------------------------------------------
__global__ __launch_bounds__(256)
void transpose_v(const u16* __restrict__ v, u16* __restrict__ vT)
{
    const int ut = blockIdx.x, h = blockIdx.y, b = blockIdx.z;
    __shared__ u16 t[64][72];
    const int tid = threadIdx.x;
    {
        const int u = tid >> 2, s4 = (tid & 3) * 16;
        const u16* src = v + ((size_t)(b * 1024 + ut * 64 + u)) * 1024 + h * 64 + s4;
        bfx8 a = *(const bfx8*)src;
        bfx8 c = *(const bfx8*)(src + 8);
#pragma unroll
        for (int k = 0; k < 8; ++k) { t[u][s4 + k] = (u16)a[k]; t[u][s4 + 8 + k] = (u16)c[k]; }
    }
    __syncthreads();
    {
        const int s = tid >> 2, u4 = (tid & 3) * 16;
        bfx8 o0, o1;
#pragma unroll
        for (int k = 0; k < 8; ++k) { o0[k] = (short)t[u4 + k][s]; o1[k] = (short)t[u4 + 8 + k][s]; }
        u16* dst = vT + ((size_t)((b * 16 + h) * 64 + s)) * 1024 + ut * 64 + u4;
        *(bfx8*)dst = o0; *(bfx8*)(dst + 8) = o1;
    }
}

// ---------------------------------------------------------------------------
// LayerNorm over E=1024, one row per block (256 thr). Output bf16 hi (+lo).
// ---------------------------------------------------------------------------
__global__ __launch_bounds__(256)
void ln_split(const float* __restrict__ x, const float* __restrict__ g,
              const float* __restrict__ be, u16* __restrict__ hhi,
              u16* __restrict__ hlo)
{
    const int row = blockIdx.x;
    const int tid = threadIdx.x;
    const float4 v = ((const float4*)(x + (size_t)row * 1024))[tid];
    float s  = v.x + v.y + v.z + v.w;
    float s2 = v.x*v.x + v.y*v.y + v.z*v.z + v.w*v.w;
#pragma unroll
    for (int m = 32; m >= 1; m >>= 1) {
        s  += __shfl_xor(s,  m, 64);
        s2 += __shfl_xor(s2, m, 64);
    }
    __shared__ float rs[4], rq[4];
    if ((tid & 63) == 0) { rs[tid >> 6] = s; rq[tid >> 6] = s2; }
    __syncthreads();
    s  = rs[0] + rs[1] + rs[2] + rs[3];
    s2 = rq[0] + rq[1] + rq[2] + rq[3];
    const float mean = s * (1.0f / 1024.0f);
    const float var  = s2 * (1.0f / 1024.0f) - mean * mean;
    const float inv  = rsqrtf(var + 1e-5f);
    const int col0 = tid * 4;
    float hv[4];
    hv[0] = (v.x - mean) * inv * g[col0+0] + be[col0+0];
    hv[1] = (v.y - mean) * inv * g[col0+1] + be[col0+1];
    hv[2] = (v.z - mean) * inv * g[col0+2] + be[col0+2];
    hv[3] = (v.w - mean) * inv * g[col0+3] + be[col0+3];
    u16v4 hb, lb;
#pragma unroll
    for (int k = 0; k < 4; ++k) {
        u16 a = f2bf(hv[k]);
        hb[k] = a;
        lb[k] = f2bf(hv[k] - bf2f(a));
    }
    *(u16v4*)(hhi + (size_t)row * 1024 + col0) = hb;
    if (hlo) *(u16v4*)(hlo + (size_t)row * 1024 + col0) = lb;
}

// ---------------------------------------------------------------------------
// GEMM (m97 128x128): C = A @ Bt^T. FLAGS: 1=bias 2=relu 4=residual 8=f32out
// ---------------------------------------------------------------------------
#define BM 128
#define BN 128
#define BKT 32

template<int FLAGS>
__global__ __launch_bounds__(256, 2)
void gemm_bt(const u16* __restrict__ A, const u16* __restrict__ Bt,
             void* __restrict__ Cout, const float* __restrict__ bias,
             const float* __restrict__ res, int M, int N, int K)
{
    __shared__ u16 As[BM * BKT];
    __shared__ u16 Bs[BN * BKT];
    const int tid  = threadIdx.x;
    const int lane = tid & 63, wave = tid >> 6;
    const int wr = wave >> 1, wc = wave & 1;
    const int li = lane & 15, lg = lane >> 4;
    const size_t m0 = (size_t)blockIdx.y * BM;
    const size_t n0 = (size_t)blockIdx.x * BN;
    f32x4 acc[4][4] = {};

    const int slot0 = tid, slot1 = tid + 256;
    const int r0 = slot0 >> 2, kc0 = (slot0 & 3) * 8;
    const int r1 = slot1 >> 2, kc1 = (slot1 & 3) * 8;

    for (int kt = 0; kt < K; kt += BKT) {
        __syncthreads();
        gl_lds16(A  + (m0 + r0) * K + kt + kc0, As + slot0 * 8);
        gl_lds16(Bt + (n0 + r0) * K + kt + kc0, Bs + slot0 * 8);
        gl_lds16(A  + (m0 + r1) * K + kt + kc1, As + slot1 * 8);
        gl_lds16(Bt + (n0 + r1) * K + kt + kc1, Bs + slot1 * 8);
        __syncthreads();
        bfx8 af[4], bfr[4];
#pragma unroll
        for (int i = 0; i < 4; ++i)
            af[i] = *(const bfx8*)&As[(wr * 64 + i * 16 + li) * BKT + lg * 8];
#pragma unroll
        for (int j = 0; j < 4; ++j)
            bfr[j] = *(const bfx8*)&Bs[(wc * 64 + j * 16 + li) * BKT + lg * 8];
#pragma unroll
        for (int i = 0; i < 4; ++i)
#pragma unroll
            for (int j = 0; j < 4; ++j)
                acc[i][j] = MFMA16(af[i], bfr[j], acc[i][j], 0, 0, 0);
    }

    float* Cf = (float*)Cout;
    u16*   Cb = (u16*)Cout;
#pragma unroll
    for (int i = 0; i < 4; ++i)
#pragma unroll
        for (int j = 0; j < 4; ++j)
#pragma unroll
            for (int r = 0; r < 4; ++r) {
                const size_t row = m0 + wr * 64 + i * 16 + lg * 4 + r;
                const size_t col = n0 + wc * 64 + j * 16 + li;
                float v = acc[i][j][r];
                if (FLAGS & 1) v += bias[col];
                if (FLAGS & 2) v = fmaxf(v, 0.0f);
                if (FLAGS & 4) v += res[row * (size_t)N + col];
                if (FLAGS & 8) Cf[row * (size_t)N + col] = v;
                else           Cb[row * (size_t)N + col] = f2bf(v);
            }
}

// ---------------------------------------------------------------------------
// 8-phase 256x256 GEMM (T2+T3+T4+T5), bias+relu, bf16 out. For ffn1:
// A[M=8192][K=1024] bf16, Bt[N=4096][K], 512 thr = 8 waves (2M x 4N),
// per-wave 128x64 out = acc[8][4]. BK=64, 2 K-tiles/iter, 8 phases.
// LDS: per op [2 buf][2 half][128 rows][64 cols] bf16, XOR-swizzled
// (byte ^= (row&7)<<4, both-sides involution). vmcnt(4) at end-P3/end-P7.
// ---------------------------------------------------------------------------
__global__ __launch_bounds__(512, 2)
void gemm8_ffn1(const u16* __restrict__ A, const u16* __restrict__ Bt,
                u16* __restrict__ C, const float* __restrict__ bias,
                int M, int N, int K)
{
    __shared__ u16 Asl[2][2][128 * 64];
    __shared__ u16 Bsl[2][2][128 * 64];
    const int tid = threadIdx.x;
    const int lane = tid & 63, wave = tid >> 6;
    const int wr = wave >> 2, wc = wave & 3;
    const int li = lane & 15, lg = lane >> 4;

    // XCD-chunked grid (512 blocks, 64/XCD), bx minor for A-panel L2 reuse
    const int bid = blockIdx.x;
    const int swz = (bid & 7) * 64 + (bid >> 3);
    const int bx = swz & 15, by = swz >> 4;
    const size_t m0 = (size_t)by * 256, n0 = (size_t)bx * 256;

    char* ldsA = (char*)&Asl[0][0][0];
    char* ldsB = (char*)&Bsl[0][0][0];

    auto stageA = [&](int j, int h) {
#pragma unroll
        for (int site = 0; site < 2; ++site) {
            const int s = tid + site * 512;
            const int r = s >> 3;
            const int cb = ((s & 7) << 4) ^ ((r & 7) << 4);
            gl_lds16((const char*)(A + (m0 + h * 128 + r) * (size_t)K + (size_t)j * 64) + cb,
                     ldsA + ((j & 1) * 2 + h) * 16384 + s * 16);
        }
    };
    auto stageB = [&](int j, int h) {
#pragma unroll
        for (int site = 0; site < 2; ++site) {
            const int s = tid + site * 512;
            const int r = s >> 3;
            const int cb = ((s & 7) << 4) ^ ((r & 7) << 4);
            gl_lds16((const char*)(Bt + (n0 + h * 128 + r) * (size_t)K + (size_t)j * 64) + cb,
                     ldsB + ((j & 1) * 2 + h) * 16384 + s * 16);
        }
    };

    const int lsw = (li & 7) << 4;
    // A-frag byte offset: buf, m-frag i, k-slot ks
    const int aHalfBase = wr * 16384;
    const int bHalfBase = (wc >> 1) * 16384;
    const int bRow0 = (wc & 1) * 64;

    f32x4 acc[8][4] = {};
    const int NT = K >> 6;      // 16 K-tiles
    const int NI = NT >> 1;     // 8 iterations

    // prologue: K0 (A+B) and K1 (B only); A(K1) staged at P0/P1 of iter 0
    stageA(0, 0); stageA(0, 1); stageB(0, 0); stageB(0, 1);
    stageB(1, 0); stageB(1, 1);
    asm volatile("s_waitcnt vmcnt(0)" ::: "memory");
    __builtin_amdgcn_sched_barrier(0);
    __builtin_amdgcn_s_barrier();
    __builtin_amdgcn_sched_barrier(0);

    for (int t = 0; t < NI; ++t) {
        const bool more = (t + 1 < NI);
#pragma unroll
        for (int half = 0; half < 2; ++half) {           // K-tile j = 2t+half
            const int buf = half;                        // j & 1
            const int abase = buf * 32768 + aHalfBase;
            const int bbase = buf * 32768 + bHalfBase;
            bfx8 bfr[4][2];
#pragma unroll
            for (int q = 0; q < 4; ++q) {                // phases
                if (q == 0) {
#pragma unroll
                    for (int nf = 0; nf < 4; ++nf)
#pragma unroll
                        for (int ks = 0; ks < 2; ++ks)
                            bfr[nf][ks] = *(const bfx8*)(ldsB + bbase
                                + (bRow0 + nf * 16 + li) * 128
                                + ((ks * 64 + lg * 16) ^ lsw));
                }
                bfx8 afr[2][2];
#pragma unroll
                for (int m = 0; m < 2; ++m)
#pragma unroll
                    for (int ks = 0; ks < 2; ++ks)
                        afr[m][ks] = *(const bfx8*)(ldsA + abase
                            + ((2 * q + m) * 16 + li) * 128
                            + ((ks * 64 + lg * 16) ^ lsw));

                // staging schedule (phase p = half*4+q):
                // P0: A0(2t+1)  P1: A1(2t+1)  P2: B0(2t+2)  P3: B1(2t+2)
                // P4: A0(2t+2)  P5: A1(2t+2)  P6: B0(2t+3)  P7: B1(2t+3)
                if (half == 0) {
                    if (q == 0) stageA(2 * t + 1, 0);
                    else if (q == 1) stageA(2 * t + 1, 1);
                    else if (q == 2) { if (more) stageB(2 * t + 2, 0); }
                    else             { if (more) stageB(2 * t + 2, 1); }
                } else {
                    if (q == 0)      { if (more) stageA(2 * t + 2, 0); }
                    else if (q == 1) { if (more) stageA(2 * t + 2, 1); }
                    else if (q == 2) { if (more) stageB(2 * t + 3, 0); }
                    else             { if (more) stageB(2 * t + 3, 1); }
                }

                __builtin_amdgcn_sched_barrier(0);
                __builtin_amdgcn_s_barrier();            // barrier 1
                asm volatile("s_waitcnt lgkmcnt(0)" ::: "memory");
                __builtin_amdgcn_sched_barrier(0);
                __builtin_amdgcn_s_setprio(1);
#pragma unroll
                for (int ks = 0; ks < 2; ++ks)
#pragma unroll
                    for (int m = 0; m < 2; ++m)
#pragma unroll
                        for (int nf = 0; nf < 4; ++nf)
                            acc[2 * q + m][nf] = MFMA16(afr[m][ks], bfr[nf][ks],
                                                        acc[2 * q + m][nf], 0, 0, 0);
                __builtin_amdgcn_s_setprio(0);
                __builtin_amdgcn_sched_barrier(0);
                if (q == 3) {                            // checkpoint end-P3 / end-P7
                    if (half == 0) {
                        if (more) { asm volatile("s_waitcnt vmcnt(4)" ::: "memory"); }
                        else      { asm volatile("s_waitcnt vmcnt(0)" ::: "memory"); }
                    } else if (more) {
                        asm volatile("s_waitcnt vmcnt(4)" ::: "memory");
                    }
                    __builtin_amdgcn_sched_barrier(0);
                }
                __builtin_amdgcn_s_barrier();            // barrier 2
                __builtin_amdgcn_sched_barrier(0);
            }
        }
    }

    // epilogue: bias + relu, bf16 out
#pragma unroll
    for (int i = 0; i < 8; ++i)
#pragma unroll
        for (int nf = 0; nf < 4; ++nf)
#pragma unroll
            for (int r = 0; r < 4; ++r) {
                const size_t row = m0 + wr * 128 + i * 16 + lg * 4 + r;
                const size_t col = n0 + wc * 64 + nf * 16 + li;
                float v = acc[i][nf][r] + bias[col];
                v = fmaxf(v, 0.0f);
                C[row * (size_t)N + col] = f2bf(v);
            }
}

// ---------------------------------------------------------------------------
// Split GEMM for Q/K: C = (Ah+Al) @ (Bh+Bl)^T, 3 passes. Output bf16 hi/lo.
// ---------------------------------------------------------------------------
__global__ __launch_bounds__(256, 2)
void gemm_qk(const u16* __restrict__ Ah, const u16* __restrict__ Al,
             const u16* __restrict__ Bh, const u16* __restrict__ Bl,
             u16* __restrict__ Ohi, u16* __restrict__ Olo,
             int M, int N, int K)
{
    __shared__ u16 Ahs[BM * BKT], Als[BM * BKT], Bhs[BN * BKT], Bls[BN * BKT];
    const int tid  = threadIdx.x;
    const int lane = tid & 63, wave = tid >> 6;
    const int wr = wave >> 1, wc = wave & 1;
    const int li = lane & 15, lg = lane >> 4;
    const size_t m0 = (size_t)blockIdx.y * BM;
    const size_t n0 = (size_t)blockIdx.x * BN;
    f32x4 acc[4][4] = {};

    const int slot0 = tid, slot1 = tid + 256;
    const int r0 = slot0 >> 2, kc0 = (slot0 & 3) * 8;
    const int r1 = slot1 >> 2, kc1 = (slot1 & 3) * 8;

    for (int kt = 0; kt < K; kt += BKT) {
        __syncthreads();
        gl_lds16(Ah + (m0 + r0) * K + kt + kc0, Ahs + slot0 * 8);
        gl_lds16(Al + (m0 + r0) * K + kt + kc0, Als + slot0 * 8);
        gl_lds16(Bh + (n0 + r0) * K + kt + kc0, Bhs + slot0 * 8);
        gl_lds16(Bl + (n0 + r0) * K + kt + kc0, Bls + slot0 * 8);
        gl_lds16(Ah + (m0 + r1) * K + kt + kc1, Ahs + slot1 * 8);
        gl_lds16(Al + (m0 + r1) * K + kt + kc1, Als + slot1 * 8);
        gl_lds16(Bh + (n0 + r1) * K + kt + kc1, Bhs + slot1 * 8);
        gl_lds16(Bl + (n0 + r1) * K + kt + kc1, Bls + slot1 * 8);
        __syncthreads();
        bfx8 ah[4], al4[4], bh[4], bl4[4];
#pragma unroll
        for (int i = 0; i < 4; ++i) {
            ah[i]  = *(const bfx8*)&Ahs[(wr * 64 + i * 16 + li) * BKT + lg * 8];
            al4[i] = *(const bfx8*)&Als[(wr * 64 + i * 16 + li) * BKT + lg * 8];
        }
#pragma unroll
        for (int j = 0; j < 4; ++j) {
            bh[j]  = *(const bfx8*)&Bhs[(wc * 64 + j * 16 + li) * BKT + lg * 8];
            bl4[j] = *(const bfx8*)&Bls[(wc * 64 + j * 16 + li) * BKT + lg * 8];
        }
#pragma unroll
        for (int i = 0; i < 4; ++i)
#pragma unroll
            for (int j = 0; j < 4; ++j) {
                acc[i][j] = MFMA16(ah[i],  bh[j],  acc[i][j], 0, 0, 0);
                acc[i][j] = MFMA16(ah[i],  bl4[j], acc[i][j], 0, 0, 0);
                acc[i][j] = MFMA16(al4[i], bh[j],  acc[i][j], 0, 0, 0);
            }
    }
#pragma unroll
    for (int i = 0; i < 4; ++i)
#pragma unroll
        for (int j = 0; j < 4; ++j)
#pragma unroll
            for (int r = 0; r < 4; ++r) {
                const size_t row = m0 + wr * 64 + i * 16 + lg * 4 + r;
                const size_t col = n0 + wc * 64 + j * 16 + li;
                const float v = acc[i][j][r];
                const u16 hi = f2bf(v);
                Ohi[row * (size_t)N + col] = hi;
                Olo[row * (size_t)N + col] = f2bf(v - bf2f(hi));
            }
}

// ---------------------------------------------------------------------------
// Causal flash attention, 2-phase pipelined (R2 structure; exp2 domain).
// ---------------------------------------------------------------------------
__global__ __launch_bounds__(256, 3)
void attn(const u16* __restrict__ qhi, const u16* __restrict__ qlo,
          const u16* __restrict__ khi, const u16* __restrict__ klo,
          const u16* __restrict__ vt, u16* __restrict__ ao)
{
    const int id  = blockIdx.x;
    const int swz = (id & 7) * 256 + (id >> 3);
    const int qt  = 15 - (swz & 15);
    const int h   = (swz >> 4) & 15;
    const int b   = swz >> 8;

    const int tid = threadIdx.x;
    const int wave = tid >> 6, lane = tid & 63;
    const int li = lane & 15, lg = lane >> 4;

    __shared__ u16 KsHi[2][4096];
    __shared__ u16 KsLo[2][4096];
    __shared__ u16 Pl[64 * 72];

    const size_t qrow = (size_t)b * 1024 + qt * 64 + wave * 16 + li;
    const size_t qoff = qrow * 1024 + h * 64 + lg * 8;
    const bfx8 qh0 = *(const bfx8*)(qhi + qoff);
    const bfx8 qh1 = *(const bfx8*)(qhi + qoff + 32);
    const bfx8 ql0 = *(const bfx8*)(qlo + qoff);
    const bfx8 ql1 = *(const bfx8*)(qlo + qoff + 32);

    f32x4 O[4] = {};
    float mrow[4] = {-1e30f, -1e30f, -1e30f, -1e30f};
    float lrow[4] = {0.f, 0.f, 0.f, 0.f};

    const int vs  = tid >> 2;
    const int vu4 = (tid & 3) * 16;
    (void)vs; (void)vu4;

    const u16* kh_base = khi + ((size_t)b * 1024) * 1024 + h * 64;
    const u16* kl_base = klo + ((size_t)b * 1024) * 1024 + h * 64;
    const u16* v_base  = vt + ((size_t)(b * 16 + h) * 64) * 1024;

    auto stageK = [&](int kt, int bufIdx) {
#pragma unroll
        for (int site = 0; site < 2; ++site) {
            const int s = tid + site * 256;
            const int r = s >> 3;
            const int cb = (((s & 7) << 4) ^ ((r & 7) << 4));
            const size_t go = ((size_t)(kt * 64 + r)) * 1024;
            gl_lds16((const char*)(kh_base + go) + cb, (char*)&KsHi[bufIdx][0] + s * 16);
            gl_lds16((const char*)(kl_base + go) + cb, (char*)&KsLo[bufIdx][0] + s * 16);
        }
    };

    const int rswz = (li & 7) << 4;

    stageK(0, 0);

    for (int kt = 0; kt <= qt; ++kt) {
        const int cur = kt & 1;

        bfx8 vld[2][4];
#pragma unroll
        for (int nf = 0; nf < 4; ++nf) {
            const u16* vr = v_base + ((size_t)(nf * 16 + li)) * 1024 + kt * 64 + lg * 8;
            vld[0][nf] = *(const bfx8*)vr;
            vld[1][nf] = *(const bfx8*)(vr + 32);
        }

        if (kt < qt) {
            stageK(kt + 1, cur ^ 1);
            asm volatile("s_waitcnt vmcnt(12)" ::: "memory");
        } else {
            asm volatile("s_waitcnt vmcnt(8)" ::: "memory");
        }
        __builtin_amdgcn_sched_barrier(0);
        __builtin_amdgcn_s_barrier();
        __builtin_amdgcn_sched_barrier(0);

        float sv[4][4];
        const char* khc = (const char*)&KsHi[cur][0];
        const char* klc = (const char*)&KsLo[cur][0];
#pragma unroll
        for (int nf = 0; nf < 4; ++nf) {
            const int rb = (nf * 16 + li) * 128;
            bfx8 kh0v = *(const bfx8*)(khc + rb + (((lg * 16) + 0 ) ^ rswz));
            bfx8 kh1v = *(const bfx8*)(khc + rb + (((lg * 16) + 64) ^ rswz));
            bfx8 kl0v = *(const bfx8*)(klc + rb + (((lg * 16) + 0 ) ^ rswz));
            bfx8 kl1v = *(const bfx8*)(klc + rb + (((lg * 16) + 64) ^ rswz));
            f32x4 a = {0.f, 0.f, 0.f, 0.f};
            a = MFMA16(qh0, kh0v, a, 0, 0, 0);
            a = MFMA16(qh1, kh1v, a, 0, 0, 0);
            a = MFMA16(qh0, kl0v, a, 0, 0, 0);
            a = MFMA16(qh1, kl1v, a, 0, 0, 0);
            a = MFMA16(ql0, kh0v, a, 0, 0, 0);
            a = MFMA16(ql1, kh1v, a, 0, 0, 0);
#pragma unroll
            for (int r = 0; r < 4; ++r) sv[nf][r] = a[r];
        }

        asm volatile("s_waitcnt lgkmcnt(0)" ::: "memory");
        __builtin_amdgcn_sched_barrier(0);
        __builtin_amdgcn_s_barrier();
        __builtin_amdgcn_sched_barrier(0);

        // scale into log2 domain: 32 * log2(e)
        const int rowg = qt * 64 + wave * 16 + lg * 4;
        const int colg = kt * 64 + li;
        float pmax[4] = {-1e30f, -1e30f, -1e30f, -1e30f};
#pragma unroll
        for (int nf = 0; nf < 4; ++nf)
#pragma unroll
            for (int r = 0; r < 4; ++r) {
                float x2 = sv[nf][r] * 46.166240905715613f;
                if (colg + nf * 16 > rowg + r) x2 = -1e30f;
                sv[nf][r] = x2;
                pmax[r] = fmaxf(pmax[r], x2);
            }
#pragma unroll
        for (int msk = 1; msk < 16; msk <<= 1)
#pragma unroll
            for (int r = 0; r < 4; ++r)
                pmax[r] = fmaxf(pmax[r], __shfl_xor(pmax[r], msk, 64));

        float alr[4], rsum[4];
#pragma unroll
        for (int r = 0; r < 4; ++r) {
            const float mnew = fmaxf(mrow[r], pmax[r]);
            alr[r] = exp2_fast(mrow[r] - mnew);
            mrow[r] = mnew;
            rsum[r] = 0.0f;
        }
        float pv[4][4];
#pragma unroll
        for (int nf = 0; nf < 4; ++nf)
#pragma unroll
            for (int r = 0; r < 4; ++r) {
                const float p = exp2_fast(sv[nf][r] - mrow[r]);
                pv[nf][r] = p;
                rsum[r] += p;
            }
#pragma unroll
        for (int msk = 1; msk < 16; msk <<= 1)
#pragma unroll
            for (int r = 0; r < 4; ++r)
                rsum[r] += __shfl_xor(rsum[r], msk, 64);
#pragma unroll
        for (int r = 0; r < 4; ++r)
            lrow[r] = lrow[r] * alr[r] + rsum[r];
#pragma unroll
        for (int nf = 0; nf < 4; ++nf)
#pragma unroll
            for (int r = 0; r < 4; ++r)
                O[nf][r] *= alr[r];

#pragma unroll
        for (int nf = 0; nf < 4; ++nf)
#pragma unroll
            for (int r = 0; r < 4; ++r)
                Pl[(wave * 16 + lg * 4 + r) * 72 + nf * 16 + li] = f2bf(pv[nf][r]);

#pragma unroll
        for (int ku = 0; ku < 2; ++ku) {
            bfx8 pf = *(const bfx8*)&Pl[(wave * 16 + li) * 72 + ku * 32 + lg * 8];
#pragma unroll
            for (int nf = 0; nf < 4; ++nf)
                O[nf] = MFMA16(pf, vld[ku][nf], O[nf], 0, 0, 0);
        }
    }

    float invl[4];
#pragma unroll
    for (int r = 0; r < 4; ++r) invl[r] = 1.0f / lrow[r];
    const size_t orow = (size_t)b * 1024 + qt * 64 + wave * 16 + lg * 4;
#pragma unroll
    for (int nf = 0; nf < 4; ++nf)
#pragma unroll
        for (int r = 0; r < 4; ++r)
            ao[(orow + r) * 1024 + h * 64 + nf * 16 + li] = f2bf(O[nf][r] * invl[r]);
}

// ---------------------------------------------------------------------------
extern "C" void kernel_launch(void* const* d_in, const int* in_sizes, int n_in,
                              void* d_out, int out_size, void* d_ws, size_t ws_size,
                              hipStream_t stream)
{
    (void)in_sizes; (void)n_in; (void)out_size; (void)ws_size;
    const float* x      = (const float*)d_in[0];
    const float* wq     = (const float*)d_in[1];
    const float* wk     = (const float*)d_in[2];
    const float* wv     = (const float*)d_in[3];
    const float* w_proj = (const float*)d_in[4];
    const float* b_proj = (const float*)d_in[5];
    const float* w1     = (const float*)d_in[6];
    const float* b1     = (const float*)d_in[7];
    const float* w2     = (const float*)d_in[8];
    const float* b2     = (const float*)d_in[9];
    const float* g1     = (const float*)d_in[10];
    const float* be1    = (const float*)d_in[11];
    const float* g2     = (const float*)d_in[12];
    const float* be2    = (const float*)d_in[13];
    float* out = (float*)d_out;

    const size_t ME2 = (size_t)8192 * 1024 * 2;   // 16 MiB (M x E bf16)
    char* wsp = (char*)d_ws;
    u16* h_hi = (u16*)(wsp + 0 * ME2);            // later reused as f2 (LN2 out)
    u16* h_lo = (u16*)(wsp + 1 * ME2);            // later reused as attn-out
    u16* q_hi = (u16*)(wsp + 2 * ME2);            // later reused as FFN act (4*ME2)
    u16* q_lo = (u16*)(wsp + 3 * ME2);
    u16* k_hi = (u16*)(wsp + 4 * ME2);
    u16* k_lo = (u16*)(wsp + 5 * ME2);
    u16* v_b  = (u16*)(wsp + 6 * ME2);
    u16* vtr  = (u16*)(wsp + 7 * ME2);
    float* y  = (float*)(wsp + 8 * ME2);          // 32 MiB f32
    char* wp0 = wsp + 8 * ME2 + (size_t)8192 * 1024 * 4;
    const size_t W1M = (size_t)1024 * 1024 * 2;   // 2 MiB
    u16* wqT_hi = (u16*)(wp0 + 0 * W1M);
    u16* wqT_lo = (u16*)(wp0 + 1 * W1M);
    u16* wkT_hi = (u16*)(wp0 + 2 * W1M);
    u16* wkT_lo = (u16*)(wp0 + 3 * W1M);
    u16* wvT    = (u16*)(wp0 + 4 * W1M);
    u16* wpT    = (u16*)(wp0 + 5 * W1M);
    u16* w1T    = (u16*)(wp0 + 6 * W1M);          // 8 MiB
    u16* w2T    = (u16*)(wp0 + 6 * W1M + 4 * W1M);
    u16* f2  = h_hi;
    u16* ao  = h_lo;
    u16* act = q_hi;   // spans q_hi..k_lo = 64 MiB = 8192*4096*2

    dim3 blk(256);

    // weight repacks (transpose to [N][K] bf16; hi/lo split for wq, wk)
    transpose_split<<<dim3(1, 16, 16), blk, 0, stream>>>(wq, wqT_hi, wqT_lo, 64, 1024, (size_t)65536, (size_t)65536);
    transpose_split<<<dim3(1, 16, 16), blk, 0, stream>>>(wk, wkT_hi, wkT_lo, 64, 1024, (size_t)65536, (size_t)65536);
    transpose_split<<<dim3(1, 16, 16), blk, 0, stream>>>(wv, wvT, nullptr, 64, 1024, (size_t)65536, (size_t)65536);
    transpose_split<<<dim3(16, 16, 1), blk, 0, stream>>>(w_proj, wpT, nullptr, 1024, 1024, 0, 0);
    transpose_split<<<dim3(64, 16, 1), blk, 0, stream>>>(w1, w1T, nullptr, 4096, 1024, 0, 0);
    transpose_split<<<dim3(16, 64, 1), blk, 0, stream>>>(w2, w2T, nullptr, 1024, 4096, 0, 0);

    // LN1 (split output)
    ln_split<<<8192, blk, 0, stream>>>(x, g1, be1, h_hi, h_lo);

    // Q, K (bf16x3 split GEMM), V (plain)
    gemm_qk<<<dim3(8, 64), blk, 0, stream>>>(h_hi, h_lo, wqT_hi, wqT_lo, q_hi, q_lo, 8192, 1024, 1024);
    gemm_qk<<<dim3(8, 64), blk, 0, stream>>>(h_hi, h_lo, wkT_hi, wkT_lo, k_hi, k_lo, 8192, 1024, 1024);
    gemm_bt<0><<<dim3(8, 64), blk, 0, stream>>>(h_hi, wvT, v_b, nullptr, nullptr, 8192, 1024, 1024);
    transpose_v<<<dim3(16, 16, 8), blk, 0, stream>>>(v_b, vtr);

    // attention (1-D grid, XCD-chunked + qt-reversed inside the kernel)
    attn<<<dim3(2048), blk, 0, stream>>>(q_hi, q_lo, k_hi, k_lo, vtr, ao);

    // proj + bias + residual(x) -> y (f32)
    gemm_bt<1 | 4 | 8><<<dim3(8, 64), blk, 0, stream>>>(ao, wpT, y, b_proj, x, 8192, 1024, 1024);

    // LN2
    ln_split<<<8192, blk, 0, stream>>>(y, g2, be2, f2, nullptr);

    // FFN1: 8-phase 256^2 (bias+relu, bf16 out)
    gemm8_ffn1<<<dim3(512), dim3(512), 0, stream>>>(f2, w1T, act, b1, 8192, 4096, 1024);
    // FFN2 (+bias+residual, f32 out)
    gemm_bt<1 | 4 | 8><<<dim3(8, 64), blk, 0, stream>>>(act, w2T, out, b2, y, 8192, 1024, 4096);
}

// Round 4
// 539.000 us; speedup vs baseline: 1.2512x; 1.0145x over previous
//
#include <hip/hip_runtime.h>

// ---------------------------------------------------------------------------
// TransformerBlock: B=8, T=1024, E=1024, H=16, HS=64, FF=4096
// bf16 MFMA (16x16x32) everywhere; bf16x3 split (hi/lo) on LN1->Q,K and QK^T
// because the reference scales scores by sqrt(T)=32 (near-one-hot softmax).
// R4: attn softmax surgery — l-tracking via ones-MFMA (no rsum shuffle chain),
// causal mask only on diagonal tile, defer-max (T13) skip of rescale.
// ---------------------------------------------------------------------------

typedef unsigned short u16;
typedef __attribute__((ext_vector_type(8))) short  bfx8;
typedef __attribute__((ext_vector_type(4))) float  f32x4;
typedef __attribute__((ext_vector_type(4))) unsigned short u16v4;

#define MFMA16 __builtin_amdgcn_mfma_f32_16x16x32_bf16

__device__ __forceinline__ u16 f2bf(float f) {
    union { float f; unsigned u; } c; c.f = f;
    unsigned r = c.u + 0x7fffu + ((c.u >> 16) & 1u);
    return (u16)(r >> 16);
}
__device__ __forceinline__ float bf2f(u16 b) {
    union { unsigned u; float f; } c; c.u = ((unsigned)b) << 16; return c.f;
}
__device__ __forceinline__ float exp2_fast(float x) {
    float r; asm("v_exp_f32 %0, %1" : "=v"(r) : "v"(x)); return r;
}

__device__ __forceinline__ void gl_lds16(const void* g, void* l) {
    void* gg = (void*)g;
    __builtin_amdgcn_global_load_lds(
        (__attribute__((address_space(1))) void*)gg,
        (__attribute__((address_space(3))) void*)l,
        16, 0, 0);
}

// ---------------------------------------------------------------------------
// Generic 64x64-tiled transpose: src f32 [R][C] (row-major) -> dst bf16 [C][R]
// ---------------------------------------------------------------------------
__global__ __launch_bounds__(256)
void transpose_split(const float* __restrict__ src, u16* __restrict__ dhi,
                     u16* __restrict__ dlo, int C, int OS,
                     size_t inBS, size_t outBS)
{
    __shared__ float t[64][65];
    const int tid = threadIdx.x;
    const float* s = src + (size_t)blockIdx.z * inBS
                   + ((size_t)blockIdx.y * 64) * C + (size_t)blockIdx.x * 64;
    const size_t obase = (size_t)blockIdx.z * outBS
                       + ((size_t)blockIdx.x * 64) * OS + (size_t)blockIdx.y * 64;
    {
        const int r = tid >> 2, c4 = (tid & 3) * 16;
#pragma unroll
        for (int k = 0; k < 4; ++k) {
            float4 f = *(const float4*)(s + (size_t)r * C + c4 + k * 4);
            t[r][c4 + k*4 + 0] = f.x; t[r][c4 + k*4 + 1] = f.y;
            t[r][c4 + k*4 + 2] = f.z; t[r][c4 + k*4 + 3] = f.w;
        }
    }
    __syncthreads();
    {
        const int c = tid >> 2, r4 = (tid & 3) * 16;
        bfx8 h0, h1, l0, l1;
#pragma unroll
        for (int k = 0; k < 8; ++k) {
            float v0 = t[r4 + k][c];
            float v1 = t[r4 + 8 + k][c];
            u16 a = f2bf(v0), b = f2bf(v1);
            h0[k] = (short)a; h1[k] = (short)b;
            l0[k] = (short)f2bf(v0 - bf2f(a));
            l1[k] = (short)f2bf(v1 - bf2f(b));
        }
        u16* d = dhi + obase + (size_t)c * OS + r4;
        *(bfx8*)d = h0; *(bfx8*)(d + 8) = h1;
        if (dlo) {
            u16* d2 = dlo + obase + (size_t)c * OS + r4;
            *(bfx8*)d2 = l0; *(bfx8*)(d2 + 8) = l1;
        }
    }
}

// ---------------------------------------------------------------------------
// V transpose: v [b*T+u][E] (col h*64+s) bf16 -> vT [(b*16+h)*64+s][T=1024]
// ---------------------------------------------------------------------------
__global__ __launch_bounds__(256)
void transpose_v(const u16* __restrict__ v, u16* __restrict__ vT)
{
    const int ut = blockIdx.x, h = blockIdx.y, b = blockIdx.z;
    __shared__ u16 t[64][72];
    const int tid = threadIdx.x;
    {
        const int u = tid >> 2, s4 = (tid & 3) * 16;
        const u16* src = v + ((size_t)(b * 1024 + ut * 64 + u)) * 1024 + h * 64 + s4;
        bfx8 a = *(const bfx8*)src;
        bfx8 c = *(const bfx8*)(src + 8);
#pragma unroll
        for (int k = 0; k < 8; ++k) { t[u][s4 + k] = (u16)a[k]; t[u][s4 + 8 + k] = (u16)c[k]; }
    }
    __syncthreads();
    {
        const int s = tid >> 2, u4 = (tid & 3) * 16;
        bfx8 o0, o1;
#pragma unroll
        for (int k = 0; k < 8; ++k) { o0[k] = (short)t[u4 + k][s]; o1[k] = (short)t[u4 + 8 + k][s]; }
        u16* dst = vT + ((size_t)((b * 16 + h) * 64 + s)) * 1024 + ut * 64 + u4;
        *(bfx8*)dst = o0; *(bfx8*)(dst + 8) = o1;
    }
}

// ---------------------------------------------------------------------------
// LayerNorm over E=1024, one row per block (256 thr). Output bf16 hi (+lo).
// ---------------------------------------------------------------------------
__global__ __launch_bounds__(256)
void ln_split(const float* __restrict__ x, const float* __restrict__ g,
              const float* __restrict__ be, u16* __restrict__ hhi,
              u16* __restrict__ hlo)
{
    const int row = blockIdx.x;
    const int tid = threadIdx.x;
    const float4 v = ((const float4*)(x + (size_t)row * 1024))[tid];
    float s  = v.x + v.y + v.z + v.w;
    float s2 = v.x*v.x + v.y*v.y + v.z*v.z + v.w*v.w;
#pragma unroll
    for (int m = 32; m >= 1; m >>= 1) {
        s  += __shfl_xor(s,  m, 64);
        s2 += __shfl_xor(s2, m, 64);
    }
    __shared__ float rs[4], rq[4];
    if ((tid & 63) == 0) { rs[tid >> 6] = s; rq[tid >> 6] = s2; }
    __syncthreads();
    s  = rs[0] + rs[1] + rs[2] + rs[3];
    s2 = rq[0] + rq[1] + rq[2] + rq[3];
    const float mean = s * (1.0f / 1024.0f);
    const float var  = s2 * (1.0f / 1024.0f) - mean * mean;
    const float inv  = rsqrtf(var + 1e-5f);
    const int col0 = tid * 4;
    float hv[4];
    hv[0] = (v.x - mean) * inv * g[col0+0] + be[col0+0];
    hv[1] = (v.y - mean) * inv * g[col0+1] + be[col0+1];
    hv[2] = (v.z - mean) * inv * g[col0+2] + be[col0+2];
    hv[3] = (v.w - mean) * inv * g[col0+3] + be[col0+3];
    u16v4 hb, lb;
#pragma unroll
    for (int k = 0; k < 4; ++k) {
        u16 a = f2bf(hv[k]);
        hb[k] = a;
        lb[k] = f2bf(hv[k] - bf2f(a));
    }
    *(u16v4*)(hhi + (size_t)row * 1024 + col0) = hb;
    if (hlo) *(u16v4*)(hlo + (size_t)row * 1024 + col0) = lb;
}

// ---------------------------------------------------------------------------
// GEMM (m97 128x128): C = A @ Bt^T. FLAGS: 1=bias 2=relu 4=residual 8=f32out
// ---------------------------------------------------------------------------
#define BM 128
#define BN 128
#define BKT 32

template<int FLAGS>
__global__ __launch_bounds__(256, 2)
void gemm_bt(const u16* __restrict__ A, const u16* __restrict__ Bt,
             void* __restrict__ Cout, const float* __restrict__ bias,
             const float* __restrict__ res, int M, int N, int K)
{
    __shared__ u16 As[BM * BKT];
    __shared__ u16 Bs[BN * BKT];
    const int tid  = threadIdx.x;
    const int lane = tid & 63, wave = tid >> 6;
    const int wr = wave >> 1, wc = wave & 1;
    const int li = lane & 15, lg = lane >> 4;
    const size_t m0 = (size_t)blockIdx.y * BM;
    const size_t n0 = (size_t)blockIdx.x * BN;
    f32x4 acc[4][4] = {};

    const int slot0 = tid, slot1 = tid + 256;
    const int r0 = slot0 >> 2, kc0 = (slot0 & 3) * 8;
    const int r1 = slot1 >> 2, kc1 = (slot1 & 3) * 8;

    for (int kt = 0; kt < K; kt += BKT) {
        __syncthreads();
        gl_lds16(A  + (m0 + r0) * K + kt + kc0, As + slot0 * 8);
        gl_lds16(Bt + (n0 + r0) * K + kt + kc0, Bs + slot0 * 8);
        gl_lds16(A  + (m0 + r1) * K + kt + kc1, As + slot1 * 8);
        gl_lds16(Bt + (n0 + r1) * K + kt + kc1, Bs + slot1 * 8);
        __syncthreads();
        bfx8 af[4], bfr[4];
#pragma unroll
        for (int i = 0; i < 4; ++i)
            af[i] = *(const bfx8*)&As[(wr * 64 + i * 16 + li) * BKT + lg * 8];
#pragma unroll
        for (int j = 0; j < 4; ++j)
            bfr[j] = *(const bfx8*)&Bs[(wc * 64 + j * 16 + li) * BKT + lg * 8];
#pragma unroll
        for (int i = 0; i < 4; ++i)
#pragma unroll
            for (int j = 0; j < 4; ++j)
                acc[i][j] = MFMA16(af[i], bfr[j], acc[i][j], 0, 0, 0);
    }

    float* Cf = (float*)Cout;
    u16*   Cb = (u16*)Cout;
#pragma unroll
    for (int i = 0; i < 4; ++i)
#pragma unroll
        for (int j = 0; j < 4; ++j)
#pragma unroll
            for (int r = 0; r < 4; ++r) {
                const size_t row = m0 + wr * 64 + i * 16 + lg * 4 + r;
                const size_t col = n0 + wc * 64 + j * 16 + li;
                float v = acc[i][j][r];
                if (FLAGS & 1) v += bias[col];
                if (FLAGS & 2) v = fmaxf(v, 0.0f);
                if (FLAGS & 4) v += res[row * (size_t)N + col];
                if (FLAGS & 8) Cf[row * (size_t)N + col] = v;
                else           Cb[row * (size_t)N + col] = f2bf(v);
            }
}

// ---------------------------------------------------------------------------
// 8-phase 256x256 GEMM (T2+T3+T4+T5), bias+relu, bf16 out (ffn1).
// ---------------------------------------------------------------------------
__global__ __launch_bounds__(512, 2)
void gemm8_ffn1(const u16* __restrict__ A, const u16* __restrict__ Bt,
                u16* __restrict__ C, const float* __restrict__ bias,
                int M, int N, int K)
{
    __shared__ u16 Asl[2][2][128 * 64];
    __shared__ u16 Bsl[2][2][128 * 64];
    const int tid = threadIdx.x;
    const int lane = tid & 63, wave = tid >> 6;
    const int wr = wave >> 2, wc = wave & 3;
    const int li = lane & 15, lg = lane >> 4;

    const int bid = blockIdx.x;
    const int swz = (bid & 7) * 64 + (bid >> 3);
    const int bx = swz & 15, by = swz >> 4;
    const size_t m0 = (size_t)by * 256, n0 = (size_t)bx * 256;

    char* ldsA = (char*)&Asl[0][0][0];
    char* ldsB = (char*)&Bsl[0][0][0];

    auto stageA = [&](int j, int h) {
#pragma unroll
        for (int site = 0; site < 2; ++site) {
            const int s = tid + site * 512;
            const int r = s >> 3;
            const int cb = ((s & 7) << 4) ^ ((r & 7) << 4);
            gl_lds16((const char*)(A + (m0 + h * 128 + r) * (size_t)K + (size_t)j * 64) + cb,
                     ldsA + ((j & 1) * 2 + h) * 16384 + s * 16);
        }
    };
    auto stageB = [&](int j, int h) {
#pragma unroll
        for (int site = 0; site < 2; ++site) {
            const int s = tid + site * 512;
            const int r = s >> 3;
            const int cb = ((s & 7) << 4) ^ ((r & 7) << 4);
            gl_lds16((const char*)(Bt + (n0 + h * 128 + r) * (size_t)K + (size_t)j * 64) + cb,
                     ldsB + ((j & 1) * 2 + h) * 16384 + s * 16);
        }
    };

    const int lsw = (li & 7) << 4;
    const int aHalfBase = wr * 16384;
    const int bHalfBase = (wc >> 1) * 16384;
    const int bRow0 = (wc & 1) * 64;

    f32x4 acc[8][4] = {};
    const int NT = K >> 6;
    const int NI = NT >> 1;

    stageA(0, 0); stageA(0, 1); stageB(0, 0); stageB(0, 1);
    stageB(1, 0); stageB(1, 1);
    asm volatile("s_waitcnt vmcnt(0)" ::: "memory");
    __builtin_amdgcn_sched_barrier(0);
    __builtin_amdgcn_s_barrier();
    __builtin_amdgcn_sched_barrier(0);

    for (int t = 0; t < NI; ++t) {
        const bool more = (t + 1 < NI);
#pragma unroll
        for (int half = 0; half < 2; ++half) {
            const int buf = half;
            const int abase = buf * 32768 + aHalfBase;
            const int bbase = buf * 32768 + bHalfBase;
            bfx8 bfr[4][2];
#pragma unroll
            for (int q = 0; q < 4; ++q) {
                if (q == 0) {
#pragma unroll
                    for (int nf = 0; nf < 4; ++nf)
#pragma unroll
                        for (int ks = 0; ks < 2; ++ks)
                            bfr[nf][ks] = *(const bfx8*)(ldsB + bbase
                                + (bRow0 + nf * 16 + li) * 128
                                + ((ks * 64 + lg * 16) ^ lsw));
                }
                bfx8 afr[2][2];
#pragma unroll
                for (int m = 0; m < 2; ++m)
#pragma unroll
                    for (int ks = 0; ks < 2; ++ks)
                        afr[m][ks] = *(const bfx8*)(ldsA + abase
                            + ((2 * q + m) * 16 + li) * 128
                            + ((ks * 64 + lg * 16) ^ lsw));

                if (half == 0) {
                    if (q == 0) stageA(2 * t + 1, 0);
                    else if (q == 1) stageA(2 * t + 1, 1);
                    else if (q == 2) { if (more) stageB(2 * t + 2, 0); }
                    else             { if (more) stageB(2 * t + 2, 1); }
                } else {
                    if (q == 0)      { if (more) stageA(2 * t + 2, 0); }
                    else if (q == 1) { if (more) stageA(2 * t + 2, 1); }
                    else if (q == 2) { if (more) stageB(2 * t + 3, 0); }
                    else             { if (more) stageB(2 * t + 3, 1); }
                }

                __builtin_amdgcn_sched_barrier(0);
                __builtin_amdgcn_s_barrier();
                asm volatile("s_waitcnt lgkmcnt(0)" ::: "memory");
                __builtin_amdgcn_sched_barrier(0);
                __builtin_amdgcn_s_setprio(1);
#pragma unroll
                for (int ks = 0; ks < 2; ++ks)
#pragma unroll
                    for (int m = 0; m < 2; ++m)
#pragma unroll
                        for (int nf = 0; nf < 4; ++nf)
                            acc[2 * q + m][nf] = MFMA16(afr[m][ks], bfr[nf][ks],
                                                        acc[2 * q + m][nf], 0, 0, 0);
                __builtin_amdgcn_s_setprio(0);
                __builtin_amdgcn_sched_barrier(0);
                if (q == 3) {
                    if (half == 0) {
                        if (more) { asm volatile("s_waitcnt vmcnt(4)" ::: "memory"); }
                        else      { asm volatile("s_waitcnt vmcnt(0)" ::: "memory"); }
                    } else if (more) {
                        asm volatile("s_waitcnt vmcnt(4)" ::: "memory");
                    }
                    __builtin_amdgcn_sched_barrier(0);
                }
                __builtin_amdgcn_s_barrier();
                __builtin_amdgcn_sched_barrier(0);
            }
        }
    }

#pragma unroll
    for (int i = 0; i < 8; ++i)
#pragma unroll
        for (int nf = 0; nf < 4; ++nf)
#pragma unroll
            for (int r = 0; r < 4; ++r) {
                const size_t row = m0 + wr * 128 + i * 16 + lg * 4 + r;
                const size_t col = n0 + wc * 64 + nf * 16 + li;
                float v = acc[i][nf][r] + bias[col];
                v = fmaxf(v, 0.0f);
                C[row * (size_t)N + col] = f2bf(v);
            }
}

// ---------------------------------------------------------------------------
// Split GEMM for Q/K: C = (Ah+Al) @ (Bh+Bl)^T, 3 passes. Output bf16 hi/lo.
// ---------------------------------------------------------------------------
__global__ __launch_bounds__(256, 2)
void gemm_qk(const u16* __restrict__ Ah, const u16* __restrict__ Al,
             const u16* __restrict__ Bh, const u16* __restrict__ Bl,
             u16* __restrict__ Ohi, u16* __restrict__ Olo,
             int M, int N, int K)
{
    __shared__ u16 Ahs[BM * BKT], Als[BM * BKT], Bhs[BN * BKT], Bls[BN * BKT];
    const int tid  = threadIdx.x;
    const int lane = tid & 63, wave = tid >> 6;
    const int wr = wave >> 1, wc = wave & 1;
    const int li = lane & 15, lg = lane >> 4;
    const size_t m0 = (size_t)blockIdx.y * BM;
    const size_t n0 = (size_t)blockIdx.x * BN;
    f32x4 acc[4][4] = {};

    const int slot0 = tid, slot1 = tid + 256;
    const int r0 = slot0 >> 2, kc0 = (slot0 & 3) * 8;
    const int r1 = slot1 >> 2, kc1 = (slot1 & 3) * 8;

    for (int kt = 0; kt < K; kt += BKT) {
        __syncthreads();
        gl_lds16(Ah + (m0 + r0) * K + kt + kc0, Ahs + slot0 * 8);
        gl_lds16(Al + (m0 + r0) * K + kt + kc0, Als + slot0 * 8);
        gl_lds16(Bh + (n0 + r0) * K + kt + kc0, Bhs + slot0 * 8);
        gl_lds16(Bl + (n0 + r0) * K + kt + kc0, Bls + slot0 * 8);
        gl_lds16(Ah + (m0 + r1) * K + kt + kc1, Ahs + slot1 * 8);
        gl_lds16(Al + (m0 + r1) * K + kt + kc1, Als + slot1 * 8);
        gl_lds16(Bh + (n0 + r1) * K + kt + kc1, Bhs + slot1 * 8);
        gl_lds16(Bl + (n0 + r1) * K + kt + kc1, Bls + slot1 * 8);
        __syncthreads();
        bfx8 ah[4], al4[4], bh[4], bl4[4];
#pragma unroll
        for (int i = 0; i < 4; ++i) {
            ah[i]  = *(const bfx8*)&Ahs[(wr * 64 + i * 16 + li) * BKT + lg * 8];
            al4[i] = *(const bfx8*)&Als[(wr * 64 + i * 16 + li) * BKT + lg * 8];
        }
#pragma unroll
        for (int j = 0; j < 4; ++j) {
            bh[j]  = *(const bfx8*)&Bhs[(wc * 64 + j * 16 + li) * BKT + lg * 8];
            bl4[j] = *(const bfx8*)&Bls[(wc * 64 + j * 16 + li) * BKT + lg * 8];
        }
#pragma unroll
        for (int i = 0; i < 4; ++i)
#pragma unroll
            for (int j = 0; j < 4; ++j) {
                acc[i][j] = MFMA16(ah[i],  bh[j],  acc[i][j], 0, 0, 0);
                acc[i][j] = MFMA16(ah[i],  bl4[j], acc[i][j], 0, 0, 0);
                acc[i][j] = MFMA16(al4[i], bh[j],  acc[i][j], 0, 0, 0);
            }
    }
#pragma unroll
    for (int i = 0; i < 4; ++i)
#pragma unroll
        for (int j = 0; j < 4; ++j)
#pragma unroll
            for (int r = 0; r < 4; ++r) {
                const size_t row = m0 + wr * 64 + i * 16 + lg * 4 + r;
                const size_t col = n0 + wc * 64 + j * 16 + li;
                const float v = acc[i][j][r];
                const u16 hi = f2bf(v);
                Ohi[row * (size_t)N + col] = hi;
                Olo[row * (size_t)N + col] = f2bf(v - bf2f(hi));
            }
}

// ---------------------------------------------------------------------------
// Causal flash attention, 2-phase pipelined. R4: l via ones-MFMA (O5),
// diagonal-only masking, defer-max skip.
// ---------------------------------------------------------------------------
__global__ __launch_bounds__(256, 3)
void attn(const u16* __restrict__ qhi, const u16* __restrict__ qlo,
          const u16* __restrict__ khi, const u16* __restrict__ klo,
          const u16* __restrict__ vt, u16* __restrict__ ao)
{
    const int id  = blockIdx.x;
    const int swz = (id & 7) * 256 + (id >> 3);
    const int qt  = 15 - (swz & 15);
    const int h   = (swz >> 4) & 15;
    const int b   = swz >> 8;

    const int tid = threadIdx.x;
    const int wave = tid >> 6, lane = tid & 63;
    const int li = lane & 15, lg = lane >> 4;

    __shared__ u16 KsHi[2][4096];
    __shared__ u16 KsLo[2][4096];
    __shared__ u16 Pl[64 * 72];

    const size_t qrow = (size_t)b * 1024 + qt * 64 + wave * 16 + li;
    const size_t qoff = qrow * 1024 + h * 64 + lg * 8;
    const bfx8 qh0 = *(const bfx8*)(qhi + qoff);
    const bfx8 qh1 = *(const bfx8*)(qhi + qoff + 32);
    const bfx8 ql0 = *(const bfx8*)(qlo + qoff);
    const bfx8 ql1 = *(const bfx8*)(qlo + qoff + 32);

    // all-ones bf16 fragment for the l-accumulator (P @ ones = row sums)
    bfx8 onesf;
#pragma unroll
    for (int k = 0; k < 8; ++k) onesf[k] = (short)0x3F80;

    f32x4 O[4] = {};
    f32x4 O5 = {0.f, 0.f, 0.f, 0.f};
    float mrow[4] = {-3e38f, -3e38f, -3e38f, -3e38f};

    const u16* kh_base = khi + ((size_t)b * 1024) * 1024 + h * 64;
    const u16* kl_base = klo + ((size_t)b * 1024) * 1024 + h * 64;
    const u16* v_base  = vt + ((size_t)(b * 16 + h) * 64) * 1024;

    auto stageK = [&](int kt, int bufIdx) {
#pragma unroll
        for (int site = 0; site < 2; ++site) {
            const int s = tid + site * 256;
            const int r = s >> 3;
            const int cb = (((s & 7) << 4) ^ ((r & 7) << 4));
            const size_t go = ((size_t)(kt * 64 + r)) * 1024;
            gl_lds16((const char*)(kh_base + go) + cb, (char*)&KsHi[bufIdx][0] + s * 16);
            gl_lds16((const char*)(kl_base + go) + cb, (char*)&KsLo[bufIdx][0] + s * 16);
        }
    };

    const int rswz = (li & 7) << 4;

    stageK(0, 0);

    for (int kt = 0; kt <= qt; ++kt) {
        const int cur = kt & 1;

        bfx8 vld[2][4];
#pragma unroll
        for (int nf = 0; nf < 4; ++nf) {
            const u16* vr = v_base + ((size_t)(nf * 16 + li)) * 1024 + kt * 64 + lg * 8;
            vld[0][nf] = *(const bfx8*)vr;
            vld[1][nf] = *(const bfx8*)(vr + 32);
        }

        if (kt < qt) {
            stageK(kt + 1, cur ^ 1);
            asm volatile("s_waitcnt vmcnt(12)" ::: "memory");
        } else {
            asm volatile("s_waitcnt vmcnt(8)" ::: "memory");
        }
        __builtin_amdgcn_sched_barrier(0);
        __builtin_amdgcn_s_barrier();
        __builtin_amdgcn_sched_barrier(0);

        float sv[4][4];
        const char* khc = (const char*)&KsHi[cur][0];
        const char* klc = (const char*)&KsLo[cur][0];
#pragma unroll
        for (int nf = 0; nf < 4; ++nf) {
            const int rb = (nf * 16 + li) * 128;
            bfx8 kh0v = *(const bfx8*)(khc + rb + (((lg * 16) + 0 ) ^ rswz));
            bfx8 kh1v = *(const bfx8*)(khc + rb + (((lg * 16) + 64) ^ rswz));
            bfx8 kl0v = *(const bfx8*)(klc + rb + (((lg * 16) + 0 ) ^ rswz));
            bfx8 kl1v = *(const bfx8*)(klc + rb + (((lg * 16) + 64) ^ rswz));
            f32x4 a = {0.f, 0.f, 0.f, 0.f};
            a = MFMA16(qh0, kh0v, a, 0, 0, 0);
            a = MFMA16(qh1, kh1v, a, 0, 0, 0);
            a = MFMA16(qh0, kl0v, a, 0, 0, 0);
            a = MFMA16(qh1, kl1v, a, 0, 0, 0);
            a = MFMA16(ql0, kh0v, a, 0, 0, 0);
            a = MFMA16(ql1, kh1v, a, 0, 0, 0);
#pragma unroll
            for (int r = 0; r < 4; ++r) sv[nf][r] = a[r];
        }

        asm volatile("s_waitcnt lgkmcnt(0)" ::: "memory");
        __builtin_amdgcn_sched_barrier(0);
        __builtin_amdgcn_s_barrier();
        __builtin_amdgcn_sched_barrier(0);

        // scale into log2 domain: 32 * log2(e)
        const float SC = 46.16624130844683f;
        float pmax[4] = {-3e38f, -3e38f, -3e38f, -3e38f};
        if (kt == qt) {
            // diagonal tile: apply causal mask
            const int rowg = qt * 64 + wave * 16 + lg * 4;
            const int colg = kt * 64 + li;
#pragma unroll
            for (int nf = 0; nf < 4; ++nf)
#pragma unroll
                for (int r = 0; r < 4; ++r) {
                    float x2 = sv[nf][r] * SC;
                    if (colg + nf * 16 > rowg + r) x2 = -3e38f;
                    sv[nf][r] = x2;
                    pmax[r] = fmaxf(pmax[r], x2);
                }
        } else {
#pragma unroll
            for (int nf = 0; nf < 4; ++nf)
#pragma unroll
                for (int r = 0; r < 4; ++r) {
                    const float x2 = sv[nf][r] * SC;
                    sv[nf][r] = x2;
                    pmax[r] = fmaxf(pmax[r], x2);
                }
        }
#pragma unroll
        for (int msk = 1; msk < 16; msk <<= 1)
#pragma unroll
            for (int r = 0; r < 4; ++r)
                pmax[r] = fmaxf(pmax[r], __shfl_xor(pmax[r], msk, 64));

        // defer-max: only rescale when a row's max grew beyond 8/ln2
        const bool grow = !__all((pmax[0] - mrow[0] <= 11.5416f) &&
                                 (pmax[1] - mrow[1] <= 11.5416f) &&
                                 (pmax[2] - mrow[2] <= 11.5416f) &&
                                 (pmax[3] - mrow[3] <= 11.5416f));
        if (grow) {
            float alr[4];
#pragma unroll
            for (int r = 0; r < 4; ++r) {
                const float mnew = fmaxf(mrow[r], pmax[r]);
                alr[r] = exp2_fast(mrow[r] - mnew);
                mrow[r] = mnew;
            }
#pragma unroll
            for (int nf = 0; nf < 4; ++nf)
#pragma unroll
                for (int r = 0; r < 4; ++r)
                    O[nf][r] *= alr[r];
#pragma unroll
            for (int r = 0; r < 4; ++r)
                O5[r] *= alr[r];
        }

        // P -> LDS (own-wave band), exp2 fused into the pack
#pragma unroll
        for (int nf = 0; nf < 4; ++nf)
#pragma unroll
            for (int r = 0; r < 4; ++r)
                Pl[(wave * 16 + lg * 4 + r) * 72 + nf * 16 + li] =
                    f2bf(exp2_fast(sv[nf][r] - mrow[r]));

        // PV MFMA (V from registers) + l via ones-column
#pragma unroll
        for (int ku = 0; ku < 2; ++ku) {
            bfx8 pf = *(const bfx8*)&Pl[(wave * 16 + li) * 72 + ku * 32 + lg * 8];
#pragma unroll
            for (int nf = 0; nf < 4; ++nf)
                O[nf] = MFMA16(pf, vld[ku][nf], O[nf], 0, 0, 0);
            O5 = MFMA16(pf, onesf, O5, 0, 0, 0);
        }
    }

    float invl[4];
#pragma unroll
    for (int r = 0; r < 4; ++r) invl[r] = 1.0f / O5[r];
    const size_t orow = (size_t)b * 1024 + qt * 64 + wave * 16 + lg * 4;
#pragma unroll
    for (int nf = 0; nf < 4; ++nf)
#pragma unroll
        for (int r = 0; r < 4; ++r)
            ao[(orow + r) * 1024 + h * 64 + nf * 16 + li] = f2bf(O[nf][r] * invl[r]);
}

// ---------------------------------------------------------------------------
extern "C" void kernel_launch(void* const* d_in, const int* in_sizes, int n_in,
                              void* d_out, int out_size, void* d_ws, size_t ws_size,
                              hipStream_t stream)
{
    (void)in_sizes; (void)n_in; (void)out_size; (void)ws_size;
    const float* x      = (const float*)d_in[0];
    const float* wq     = (const float*)d_in[1];
    const float* wk     = (const float*)d_in[2];
    const float* wv     = (const float*)d_in[3];
    const float* w_proj = (const float*)d_in[4];
    const float* b_proj = (const float*)d_in[5];
    const float* w1     = (const float*)d_in[6];
    const float* b1     = (const float*)d_in[7];
    const float* w2     = (const float*)d_in[8];
    const float* b2     = (const float*)d_in[9];
    const float* g1     = (const float*)d_in[10];
    const float* be1    = (const float*)d_in[11];
    const float* g2     = (const float*)d_in[12];
    const float* be2    = (const float*)d_in[13];
    float* out = (float*)d_out;

    const size_t ME2 = (size_t)8192 * 1024 * 2;   // 16 MiB (M x E bf16)
    char* wsp = (char*)d_ws;
    u16* h_hi = (u16*)(wsp + 0 * ME2);            // later reused as f2 (LN2 out)
    u16* h_lo = (u16*)(wsp + 1 * ME2);            // later reused as attn-out
    u16* q_hi = (u16*)(wsp + 2 * ME2);            // later reused as FFN act (4*ME2)
    u16* q_lo = (u16*)(wsp + 3 * ME2);
    u16* k_hi = (u16*)(wsp + 4 * ME2);
    u16* k_lo = (u16*)(wsp + 5 * ME2);
    u16* v_b  = (u16*)(wsp + 6 * ME2);
    u16* vtr  = (u16*)(wsp + 7 * ME2);
    float* y  = (float*)(wsp + 8 * ME2);          // 32 MiB f32
    char* wp0 = wsp + 8 * ME2 + (size_t)8192 * 1024 * 4;
    const size_t W1M = (size_t)1024 * 1024 * 2;   // 2 MiB
    u16* wqT_hi = (u16*)(wp0 + 0 * W1M);
    u16* wqT_lo = (u16*)(wp0 + 1 * W1M);
    u16* wkT_hi = (u16*)(wp0 + 2 * W1M);
    u16* wkT_lo = (u16*)(wp0 + 3 * W1M);
    u16* wvT    = (u16*)(wp0 + 4 * W1M);
    u16* wpT    = (u16*)(wp0 + 5 * W1M);
    u16* w1T    = (u16*)(wp0 + 6 * W1M);          // 8 MiB
    u16* w2T    = (u16*)(wp0 + 6 * W1M + 4 * W1M);
    u16* f2  = h_hi;
    u16* ao  = h_lo;
    u16* act = q_hi;   // spans q_hi..k_lo = 64 MiB = 8192*4096*2

    dim3 blk(256);

    // weight repacks (transpose to [N][K] bf16; hi/lo split for wq, wk)
    transpose_split<<<dim3(1, 16, 16), blk, 0, stream>>>(wq, wqT_hi, wqT_lo, 64, 1024, (size_t)65536, (size_t)65536);
    transpose_split<<<dim3(1, 16, 16), blk, 0, stream>>>(wk, wkT_hi, wkT_lo, 64, 1024, (size_t)65536, (size_t)65536);
    transpose_split<<<dim3(1, 16, 16), blk, 0, stream>>>(wv, wvT, nullptr, 64, 1024, (size_t)65536, (size_t)65536);
    transpose_split<<<dim3(16, 16, 1), blk, 0, stream>>>(w_proj, wpT, nullptr, 1024, 1024, 0, 0);
    transpose_split<<<dim3(64, 16, 1), blk, 0, stream>>>(w1, w1T, nullptr, 4096, 1024, 0, 0);
    transpose_split<<<dim3(16, 64, 1), blk, 0, stream>>>(w2, w2T, nullptr, 1024, 4096, 0, 0);

    // LN1 (split output)
    ln_split<<<8192, blk, 0, stream>>>(x, g1, be1, h_hi, h_lo);

    // Q, K (bf16x3 split GEMM), V (plain)
    gemm_qk<<<dim3(8, 64), blk, 0, stream>>>(h_hi, h_lo, wqT_hi, wqT_lo, q_hi, q_lo, 8192, 1024, 1024);
    gemm_qk<<<dim3(8, 64), blk, 0, stream>>>(h_hi, h_lo, wkT_hi, wkT_lo, k_hi, k_lo, 8192, 1024, 1024);
    gemm_bt<0><<<dim3(8, 64), blk, 0, stream>>>(h_hi, wvT, v_b, nullptr, nullptr, 8192, 1024, 1024);
    transpose_v<<<dim3(16, 16, 8), blk, 0, stream>>>(v_b, vtr);

    // attention (1-D grid, XCD-chunked + qt-reversed inside the kernel)
    attn<<<dim3(2048), blk, 0, stream>>>(q_hi, q_lo, k_hi, k_lo, vtr, ao);

    // proj + bias + residual(x) -> y (f32)
    gemm_bt<1 | 4 | 8><<<dim3(8, 64), blk, 0, stream>>>(ao, wpT, y, b_proj, x, 8192, 1024, 1024);

    // LN2
    ln_split<<<8192, blk, 0, stream>>>(y, g2, be2, f2, nullptr);

    // FFN1: 8-phase 256^2 (bias+relu, bf16 out)
    gemm8_ffn1<<<dim3(512), dim3(512), 0, stream>>>(f2, w1T, act, b1, 8192, 4096, 1024);
    // FFN2 (+bias+residual, f32 out)
    gemm_bt<1 | 4 | 8><<<dim3(8, 64), blk, 0, stream>>>(act, w2T, out, b2, y, 8192, 1024, 4096);
}